// Round 14
// baseline (250.168 us; speedup 1.0000x reference)
//
#include <hip/hip_runtime.h>
#include <hip/hip_bf16.h>

// TalkingHeads: BS=2, C_IN=512, SEQ=1024, DK=DV=64, H=16. fp32 I/O.
// Round 26: (1) opartP back to (256,3) -- r13's (256,4) starved regs to 52
// (no spill, but 57.5 vs 52.7 us; occupancy 22/34/38% <-> 59/52.7/57.5 us:
// occupancy exonerated, latency-bound at any occupancy). (2) osum fused into
// ath_outf for the P path: KSO=4 partials summed in staging (3 extra
// coalesced loads/tile vs r11's failed 8-strided version); removes one
// kernel + launch + 8 MB round-trip. Tests the ~70us launch-gap hypothesis.
// Legacy fallback path keeps separate osum + plain out.

#define B_S  2
#define C_INN 512
#define SEQL 1024
#define D_K  64
#define N_H  16
#define BQJ  (2 * 1024 * 1024)   // elements of one O partial [b][q][j]
#define KSL  16                  // lpart split (lp has KSL*4 per-wave slots)
#define KSO  4                   // opart split (P path)
#define KSO_LEG 8                // legacy fallback opart split

typedef __attribute__((ext_vector_type(4))) float floatx4;
typedef __attribute__((ext_vector_type(8))) short short8;
typedef __attribute__((ext_vector_type(2))) unsigned int uint2v;
typedef __fp16 h2raw __attribute__((ext_vector_type(2)));
typedef _Float16 f16x4 __attribute__((ext_vector_type(4)));

static __device__ __forceinline__ float bf2f(unsigned short u) {
  union { unsigned int i; float f; } x; x.i = ((unsigned int)u) << 16; return x.f;
}
static __device__ __forceinline__ unsigned short f2bf(float f) {
  union { float f; unsigned int i; } x; x.f = f;
  return (unsigned short)((x.i + 0x7fffu + ((x.i >> 16) & 1u)) >> 16);
}
static __device__ __forceinline__ unsigned int pkh2(float a, float b) {
  h2raw r = __builtin_amdgcn_cvt_pkrtz(a, b);
  union { h2raw h; unsigned int u; } x; x.h = r; return x.u;
}
static __device__ __forceinline__ unsigned int pkbf(float a, float b) {
  return (unsigned int)f2bf(a) | ((unsigned int)f2bf(b) << 16);
}
static __device__ __forceinline__ f16x4 mkh4(unsigned int a, unsigned int b) {
  union { unsigned int u[2]; f16x4 h; } x; x.u[0] = a; x.u[1] = b; return x.h;
}

// ---------------------------------------------------------------------------
// K0: batched transpose+convert. z: 0,1=inp b0/b1 (512x1024 -> [s][c]);
// 2,3,4=Wq/Wk/Wv (512x1024 -> [n][c]); 5=Wo (1024x512 -> [co][j]). bf16 out.
// ---------------------------------------------------------------------------
__global__ __launch_bounds__(256) void ath_tr(
    const float* __restrict__ inp, const float* __restrict__ Wq,
    const float* __restrict__ Wk,  const float* __restrict__ Wv,
    const float* __restrict__ Wo,
    unsigned short* __restrict__ inpT, unsigned short* __restrict__ WT,
    unsigned short* __restrict__ WoT)
{
  const int z = blockIdx.z;
  const float* src; unsigned short* dst; int R, C;
  if      (z == 0) { src = inp;              dst = inpT;                R = 512;  C = 1024; }
  else if (z == 1) { src = inp + 512 * 1024; dst = inpT + 1024 * 512;   R = 512;  C = 1024; }
  else if (z == 2) { src = Wq;               dst = WT;                  R = 512;  C = 1024; }
  else if (z == 3) { src = Wk;               dst = WT + 1024 * 512;     R = 512;  C = 1024; }
  else if (z == 4) { src = Wv;               dst = WT + 2 * 1024 * 512; R = 512;  C = 1024; }
  else             { src = Wo;               dst = WoT;                 R = 1024; C = 512;  }
  const int ct = blockIdx.x, rt = blockIdx.y;
  if (ct * 32 >= C || rt * 32 >= R) return;

  __shared__ float Ts[32][33];
  const int t = threadIdx.x;
  {
    const int r = t >> 3, c4 = (t & 7) * 4;
    const floatx4 g = *(const floatx4*)(src + (size_t)(rt * 32 + r) * C + ct * 32 + c4);
    Ts[r][c4 + 0] = g[0]; Ts[r][c4 + 1] = g[1];
    Ts[r][c4 + 2] = g[2]; Ts[r][c4 + 3] = g[3];
  }
  __syncthreads();
  {
    const int i = t >> 3, k4 = (t & 7) * 4;
    const unsigned int o0 = pkbf(Ts[k4 + 0][i], Ts[k4 + 1][i]);
    const unsigned int o1 = pkbf(Ts[k4 + 2][i], Ts[k4 + 3][i]);
    *(uint2v*)(dst + (size_t)(ct * 32 + i) * R + rt * 32 + k4) = (uint2v){o0, o1};
  }
}

// ---------------------------------------------------------------------------
// K1: QKV projection from pre-transposed bf16 inputs.
// Q,K -> [b][h][s][d] ; V -> [b][v][d][s]. Staging = b128 row copies.
// ---------------------------------------------------------------------------
__global__ __launch_bounds__(256) void ath_qkv(
    const unsigned short* __restrict__ inpT,  // [b][s][c]
    const unsigned short* __restrict__ WT,    // [p][n][c]
    const float* __restrict__ Aq,
    const float* __restrict__ Ak,
    const float* __restrict__ Av,
    unsigned short* __restrict__ ws)
{
  const int sblk = blockIdx.x;
  const int nblk = blockIdx.y;
  const int z = blockIdx.z;
  const int b = z / 3, p = z % 3;
  const float* Ap = (p == 0) ? Aq : ((p == 1) ? Ak : Av);
  const float sig = 1.0f / (1.0f + __expf(-Ap[0]));

  __shared__ __align__(16) unsigned short As[64][40];
  __shared__ __align__(16) unsigned short Bs[64][40];

  const int tid = threadIdx.x;
  const int w = tid >> 6, lane = tid & 63;
  const int l15 = lane & 15, quad = lane >> 4;
  const int srow = tid >> 2, sc8 = (tid & 3) * 8;

  floatx4 acc[4];
#pragma unroll
  for (int i = 0; i < 4; ++i) acc[i] = (floatx4){0.f, 0.f, 0.f, 0.f};

  for (int cc = 0; cc < 16; ++cc) {
    const int c0 = cc * 32;
    __syncthreads();
    *(short8*)&As[srow][sc8] =
        *(const short8*)(inpT + ((size_t)(b * 1024 + sblk * 64 + srow)) * 512 + c0 + sc8);
    *(short8*)&Bs[srow][sc8] =
        *(const short8*)(WT + ((size_t)(p * 1024 + nblk * 64 + srow)) * 512 + c0 + sc8);
    __syncthreads();
    const short8 a = *(const short8*)&As[w * 16 + l15][quad * 8];
#pragma unroll
    for (int nt = 0; nt < 4; ++nt) {
      const short8 bb = *(const short8*)&Bs[nt * 16 + l15][quad * 8];
      acc[nt] = __builtin_amdgcn_mfma_f32_16x16x32_bf16(a, bb, acc[nt], 0, 0, 0);
    }
  }

  unsigned short* out = ws + (size_t)p * ((size_t)B_S * N_H * SEQL * D_K);
#pragma unroll
  for (int nt = 0; nt < 4; ++nt) {
    const int h = l15;
    const int d = nblk * 4 + nt;
#pragma unroll
    for (int r = 0; r < 4; ++r) {
      const int s = sblk * 64 + w * 16 + quad * 4 + r;
      const float vout = acc[nt][r] * sig;
      if (p == 2) out[((size_t)((b * N_H + h) * D_K + d)) * SEQL + s] = f2bf(vout);
      else        out[((size_t)((b * N_H + h) * SEQL + s)) * D_K + d] = f2bf(vout);
    }
  }
}

// ---------------------------------------------------------------------------
// K2a (P path): partial l + P store; proven (256,3).
// ---------------------------------------------------------------------------
__global__ __launch_bounds__(256, 3) void ath_lpartP(
    const float* __restrict__ maskp,
    const float* __restrict__ Wl,
    const unsigned short* __restrict__ qkv,
    float* __restrict__ lp,
    unsigned short* __restrict__ Pws)
{
  const int qblk = blockIdx.x;
  const int ks   = blockIdx.y;
  const int b    = blockIdx.z;
  const int tid = threadIdx.x;
  const int w = tid >> 6, lane = tid & 63;
  const int l15 = lane & 15, quad = lane >> 4;

  const unsigned short* Qf = qkv;
  const unsigned short* Kf = qkv + (size_t)B_S * N_H * SEQL * D_K;

  __shared__ unsigned int JtU[9216];  // [q16*64 + k][9] f16 pairs, 36 KB

  const f16x4 wlA = mkh4(pkh2(Wl[(quad * 4 + 0) * 16 + l15], Wl[(quad * 4 + 1) * 16 + l15]),
                         pkh2(Wl[(quad * 4 + 2) * 16 + l15], Wl[(quad * 4 + 3) * 16 + l15]));
  const f16x4 idB = mkh4(pkh2((quad * 4 + 0 == l15) ? 1.f : 0.f, (quad * 4 + 1 == l15) ? 1.f : 0.f),
                         pkh2((quad * 4 + 2 == l15) ? 1.f : 0.f, (quad * 4 + 3 == l15) ? 1.f : 0.f));
  const unsigned int ONE2 = 0x3C003C00u;
  const f16x4 onesB = mkh4(ONE2, ONE2);
  const f16x4 zeroB = mkh4(0u, 0u);

  const float mreg = maskp[b * SEQL + ks * 64 + w * 16 + l15];  // mask[k=l15]
  const int k0 = ks * 64;
  const int kabs = k0 + w * 16 + l15;

  short8 qf0[4], qf1[4];
#pragma unroll
  for (int hh = 0; hh < 4; ++hh) {
    const unsigned short* qb =
        Qf + ((size_t)((b * N_H + w * 4 + hh) * SEQL) + qblk * 16 + l15) * D_K;
    qf0[hh] = *(const short8*)(qb + quad * 8);
    qf1[hh] = *(const short8*)(qb + 32 + quad * 8);
  }

#pragma unroll
  for (int kt = 0; kt < 4; ++kt) {
    floatx4 jc[4];
#pragma unroll
    for (int hh = 0; hh < 4; ++hh) {
      const unsigned short* kb =
          Kf + ((size_t)((b * N_H + w * 4 + hh) * SEQL) + k0 + kt * 16 + l15) * D_K;
      const short8 kf0 = *(const short8*)(kb + quad * 8);
      const short8 kf1 = *(const short8*)(kb + 32 + quad * 8);
      floatx4 c = (floatx4){0.f, 0.f, 0.f, 0.f};
      c = __builtin_amdgcn_mfma_f32_16x16x32_bf16(qf0[hh], kf0, c, 0, 0, 0);
      c = __builtin_amdgcn_mfma_f32_16x16x32_bf16(qf1[hh], kf1, c, 0, 0, 0);
      jc[hh] = c;
    }
#pragma unroll
    for (int r = 0; r < 4; ++r) {
      const int base = ((quad * 4 + r) * 64 + kt * 16 + l15) * 9 + w * 2;
      JtU[base + 0] = pkh2(jc[0][r], jc[1][r]);
      JtU[base + 1] = pkh2(jc[2][r], jc[3][r]);
    }
  }

  __syncthreads();  // JtU complete (all waves' h-pairs)

  unsigned int* Pu = (unsigned int*)Pws;
  floatx4 dl0 = (floatx4){0.f, 0.f, 0.f, 0.f};
  floatx4 dl1 = (floatx4){0.f, 0.f, 0.f, 0.f};
#pragma unroll 4
  for (int q = 0; q < 16; ++q) {
    const int jb = (q * 64 + w * 16 + l15) * 9 + quad * 2;   // B[h=quad*4+j][k=l15]
    const f16x4 bj = mkh4(JtU[jb], JtU[jb + 1]);
    floatx4 d1 = __builtin_amdgcn_mfma_f32_16x16x16f16(
        wlA, bj, (floatx4){0.f, 0.f, 0.f, 0.f}, 0, 0, 0);  // (g rows, k cols)
    float p[4];
#pragma unroll
    for (int r = 0; r < 4; ++r) {
      const float e = fminf(fmaxf(d1[r] - mreg, -60.f), 60.f);
      p[r] = __expf(e);
    }
    const unsigned int u0 = pkh2(p[0], p[1]);
    const unsigned int u1 = pkh2(p[2], p[3]);
    const size_t pidx =
        ((size_t)(b * 1024 + qblk * 16 + q) * 1024 + kabs) * 8 + quad * 2;
    *(uint2v*)&Pu[pidx] = (uint2v){u0, u1};

    const f16x4 ap = mkh4(u0, u1);
    floatx4 dt = __builtin_amdgcn_mfma_f32_16x16x16f16(
        ap, idB, (floatx4){0.f, 0.f, 0.f, 0.f}, 0, 0, 0);   // (k rows, g cols)
    const f16x4 a2 = mkh4(pkh2(dt[0], dt[1]), pkh2(dt[2], dt[3]));  // A[g][k]
    const f16x4 eq = (l15 == q) ? onesB : zeroB;  // B[k][col]=delta(col,q)
    if (q & 1) dl1 = __builtin_amdgcn_mfma_f32_16x16x16f16(a2, eq, dl1, 0, 0, 0);
    else       dl0 = __builtin_amdgcn_mfma_f32_16x16x16f16(a2, eq, dl0, 0, 0, 0);
  }
  const floatx4 dl = dl0 + dl1;

  *(floatx4*)(lp + ((size_t)((ks * 4 + w) * 2 + b)) * 16384 +
              (size_t)(qblk * 16 + l15) * 16 + quad * 4) = dl;
}

// ---------------------------------------------------------------------------
// K2a (fallback): legacy lpart, identical to r18.
// ---------------------------------------------------------------------------
__global__ __launch_bounds__(256, 3) void ath_lpart(
    const float* __restrict__ maskp,
    const float* __restrict__ Wl,
    const unsigned short* __restrict__ qkv,
    float* __restrict__ lp)
{
  const int qblk = blockIdx.x;
  const int ks   = blockIdx.y;
  const int b    = blockIdx.z;
  const int tid = threadIdx.x;
  const int w = tid >> 6, lane = tid & 63;
  const int l15 = lane & 15, quad = lane >> 4;

  const unsigned short* Qf = qkv;
  const unsigned short* Kf = qkv + (size_t)B_S * N_H * SEQL * D_K;

  __shared__ unsigned int JtU[9216];

  const f16x4 wlA = mkh4(pkh2(Wl[(quad * 4 + 0) * 16 + l15], Wl[(quad * 4 + 1) * 16 + l15]),
                         pkh2(Wl[(quad * 4 + 2) * 16 + l15], Wl[(quad * 4 + 3) * 16 + l15]));
  const f16x4 idB = mkh4(pkh2((quad * 4 + 0 == l15) ? 1.f : 0.f, (quad * 4 + 1 == l15) ? 1.f : 0.f),
                         pkh2((quad * 4 + 2 == l15) ? 1.f : 0.f, (quad * 4 + 3 == l15) ? 1.f : 0.f));
  const unsigned int ONE2 = 0x3C003C00u;
  const f16x4 onesB = mkh4(ONE2, ONE2);
  const f16x4 zeroB = mkh4(0u, 0u);

  const float mreg = maskp[b * SEQL + ks * 64 + w * 16 + l15];
  const int k0 = ks * 64;

  short8 qf0[4], qf1[4];
#pragma unroll
  for (int hh = 0; hh < 4; ++hh) {
    const unsigned short* qb =
        Qf + ((size_t)((b * N_H + w * 4 + hh) * SEQL) + qblk * 16 + l15) * D_K;
    qf0[hh] = *(const short8*)(qb + quad * 8);
    qf1[hh] = *(const short8*)(qb + 32 + quad * 8);
  }

#pragma unroll
  for (int kt = 0; kt < 4; ++kt) {
    floatx4 jc[4];
#pragma unroll
    for (int hh = 0; hh < 4; ++hh) {
      const unsigned short* kb =
          Kf + ((size_t)((b * N_H + w * 4 + hh) * SEQL) + k0 + kt * 16 + l15) * D_K;
      const short8 kf0 = *(const short8*)(kb + quad * 8);
      const short8 kf1 = *(const short8*)(kb + 32 + quad * 8);
      floatx4 c = (floatx4){0.f, 0.f, 0.f, 0.f};
      c = __builtin_amdgcn_mfma_f32_16x16x32_bf16(qf0[hh], kf0, c, 0, 0, 0);
      c = __builtin_amdgcn_mfma_f32_16x16x32_bf16(qf1[hh], kf1, c, 0, 0, 0);
      jc[hh] = c;
    }
#pragma unroll
    for (int r = 0; r < 4; ++r) {
      const int base = ((quad * 4 + r) * 64 + kt * 16 + l15) * 9 + w * 2;
      JtU[base + 0] = pkh2(jc[0][r], jc[1][r]);
      JtU[base + 1] = pkh2(jc[2][r], jc[3][r]);
    }
  }

  __syncthreads();

  floatx4 dl0 = (floatx4){0.f, 0.f, 0.f, 0.f};
  floatx4 dl1 = (floatx4){0.f, 0.f, 0.f, 0.f};
#pragma unroll 4
  for (int q = 0; q < 16; ++q) {
    const int jb = (q * 64 + w * 16 + l15) * 9 + quad * 2;
    const f16x4 bj = mkh4(JtU[jb], JtU[jb + 1]);
    floatx4 d1 = __builtin_amdgcn_mfma_f32_16x16x16f16(
        wlA, bj, (floatx4){0.f, 0.f, 0.f, 0.f}, 0, 0, 0);
    float p[4];
#pragma unroll
    for (int r = 0; r < 4; ++r) {
      const float e = fminf(fmaxf(d1[r] - mreg, -60.f), 60.f);
      p[r] = __expf(e);
    }
    const f16x4 ap = mkh4(pkh2(p[0], p[1]), pkh2(p[2], p[3]));
    floatx4 dt = __builtin_amdgcn_mfma_f32_16x16x16f16(
        ap, idB, (floatx4){0.f, 0.f, 0.f, 0.f}, 0, 0, 0);
    const f16x4 a2 = mkh4(pkh2(dt[0], dt[1]), pkh2(dt[2], dt[3]));
    const f16x4 eq = (l15 == q) ? onesB : zeroB;
    if (q & 1) dl1 = __builtin_amdgcn_mfma_f32_16x16x16f16(a2, eq, dl1, 0, 0, 0);
    else       dl0 = __builtin_amdgcn_mfma_f32_16x16x16f16(a2, eq, dl0, 0, 0, 0);
  }
  const floatx4 dl = dl0 + dl1;

  *(floatx4*)(lp + ((size_t)((ks * 4 + w) * 2 + b)) * 16384 +
              (size_t)(qblk * 16 + l15) * 16 + quad * 4) = dl;
}

// ---------------------------------------------------------------------------
// K2r: invl = 1 / sum over KSL*4 per-wave slots. grid(128, 256 thr).
// ---------------------------------------------------------------------------
__global__ __launch_bounds__(256) void ath_linv(
    const float* __restrict__ lp, float* __restrict__ invl)
{
  const int t = blockIdx.x * 256 + threadIdx.x;
  const int b = t >> 14, rem = t & 16383;
  float s = 0.f;
#pragma unroll
  for (int sl = 0; sl < KSL * 4; ++sl) s += lp[(size_t)(sl * 2 + b) * 16384 + rem];
  invl[t] = 1.0f / fmaxf(s, 1e-37f);
}

// ---------------------------------------------------------------------------
// K2b (P path): d-split partial O, KSO=4 (k-256/block over 4 rds).
// grid(64, 4, 4: z=b*2+dh) = 1024 blocks; (256,3) = best measured config.
// ---------------------------------------------------------------------------
__global__ __launch_bounds__(256, 3) void ath_opartP(
    const unsigned short* __restrict__ Pws,   // [b][q][k][g16] f16 unnorm
    const float* __restrict__ Ww,
    const unsigned short* __restrict__ qkv,
    const float* __restrict__ invl,
    unsigned short* __restrict__ Obp)
{
  const int qblk = blockIdx.x;
  const int ks   = blockIdx.y;
  const int z    = blockIdx.z;          // b*2 + dh
  const int b = z >> 1, dh = z & 1;
  const int tid = threadIdx.x;
  const int w = tid >> 6, lane = tid & 63;
  const int l15 = lane & 15, quad = lane >> 4;

  const unsigned short* Vf = qkv + 2 * (size_t)B_S * N_H * SEQL * D_K;

  __shared__ __align__(16) unsigned short Us[16 * 16 * 64];  // 32 KB, swizzled
  __shared__ float invls[16][16];

  invls[tid >> 4][tid & 15] =
      invl[(size_t)b * 16384 + (qblk * 16 + (tid >> 4)) * 16 + (tid & 15)];

  const f16x4 wwB = mkh4(pkh2(Ww[(quad * 4 + 0) * 16 + l15], Ww[(quad * 4 + 1) * 16 + l15]),
                         pkh2(Ww[(quad * 4 + 2) * 16 + l15], Ww[(quad * 4 + 3) * 16 + l15]));

  floatx4 oacc[4][2];
#pragma unroll
  for (int a = 0; a < 4; ++a)
#pragma unroll
    for (int d = 0; d < 2; ++d) oacc[a][d] = (floatx4){0.f, 0.f, 0.f, 0.f};

  const unsigned int* Pu = (const unsigned int*)Pws;

  __syncthreads();  // invls visible

  for (int rd = 0; rd < 4; ++rd) {
    const int kabs = ks * 256 + rd * 64 + w * 16 + l15;

    // ---- mix: read P (batches of 8 q), x inv, U-mfma, swizzled Us write ----
#pragma unroll
    for (int qh = 0; qh < 2; ++qh) {
      uint2v pv[8];
#pragma unroll
      for (int qq = 0; qq < 8; ++qq) {
        const size_t pidx =
            ((size_t)(b * 1024 + qblk * 16 + qh * 8 + qq) * 1024 + kabs) * 8 + quad * 2;
        pv[qq] = *(const uint2v*)&Pu[pidx];
      }
#pragma unroll
      for (int qq = 0; qq < 8; ++qq) {
        const int q = qh * 8 + qq;
        const floatx4 iq = *(const floatx4*)&invls[q][quad * 4];
        union { unsigned int u; _Float16 h[2]; } z0, z1;
        z0.u = pv[qq][0]; z1.u = pv[qq][1];
        const f16x4 ap = mkh4(pkh2((float)z0.h[0] * iq[0], (float)z0.h[1] * iq[1]),
                              pkh2((float)z1.h[0] * iq[2], (float)z1.h[1] * iq[3]));
        floatx4 d2 = __builtin_amdgcn_mfma_f32_16x16x16f16(
            ap, wwB, (floatx4){0.f, 0.f, 0.f, 0.f}, 0, 0, 0);  // U: k rows, v=l15
        const int row = l15 * 16 + q;
        const int ch = (w * 2 + (quad >> 1)) ^ ((l15 ^ q) & 7);
        *(uint2v*)&Us[row * 64 + ch * 8 + (quad & 1) * 4] =
            (uint2v){pkbf(d2[0], d2[1]), pkbf(d2[2], d2[3])};
      }
    }

    __syncthreads();  // all waves' Us slices ready

    // ---- V-phase: wave w -> v = 4w..4w+3; d-tiles dh*2+dt (dt 0..1) ----
#pragma unroll
    for (int tp = 0; tp < 2; ++tp) {
      const int kt_abs = ks * 256 + rd * 64 + tp * 32;
#pragma unroll
      for (int vv = 0; vv < 4; ++vv) {
        const int v = w * 4 + vv;
        const int ch = (tp * 4 + quad) ^ ((v ^ l15) & 7);
        const short8 ufr = *(const short8*)&Us[(v * 16 + l15) * 64 + ch * 8];
#pragma unroll
        for (int dt = 0; dt < 2; ++dt) {
          const int dtile = dh * 2 + dt;
          const short8 vfr = *(const short8*)(Vf +
              ((size_t)((b * N_H + v) * D_K + dtile * 16 + l15)) * SEQL + kt_abs + quad * 8);
          oacc[vv][dt] = __builtin_amdgcn_mfma_f32_16x16x32_bf16(ufr, vfr, oacc[vv][dt], 0, 0, 0);
        }
      }
    }

    __syncthreads();  // Us free for next rd
  }

#pragma unroll
  for (int vv = 0; vv < 4; ++vv) {
    const int v = w * 4 + vv;
#pragma unroll
    for (int dt = 0; dt < 2; ++dt) {
      const int d = (dh * 2 + dt) * 16 + l15;
#pragma unroll
      for (int r = 0; r < 4; ++r) {
        const int q = qblk * 16 + quad * 4 + r;
        Obp[(size_t)ks * BQJ + ((size_t)(b * SEQL + q)) * 1024 + d * 16 + v] = f2bf(oacc[vv][dt][r]);
      }
    }
  }
}

// ---------------------------------------------------------------------------
// K2b (fallback): legacy opart, identical to r18 (KSO_LEG=8 split).
// ---------------------------------------------------------------------------
__global__ __launch_bounds__(256, 2) void ath_opart(
    const float* __restrict__ maskp,
    const float* __restrict__ Wl,
    const float* __restrict__ Ww,
    const unsigned short* __restrict__ qkv,
    const float* __restrict__ invl,
    unsigned short* __restrict__ Obp)
{
  const int qblk = blockIdx.x;
  const int ks   = blockIdx.y;
  const int b    = blockIdx.z;
  const int tid = threadIdx.x;
  const int w = tid >> 6, lane = tid & 63;
  const int l15 = lane & 15, quad = lane >> 4;

  const unsigned short* Qf = qkv;
  const unsigned short* Kf = qkv + (size_t)B_S * N_H * SEQL * D_K;
  const unsigned short* Vf = qkv + 2 * (size_t)B_S * N_H * SEQL * D_K;

  __shared__ unsigned int JtU[9216];
  __shared__ float invls[16][16];

  invls[tid >> 4][tid & 15] =
      invl[(size_t)b * 16384 + (qblk * 16 + (tid >> 4)) * 16 + (tid & 15)];

  const f16x4 wlA = mkh4(pkh2(Wl[(quad * 4 + 0) * 16 + l15], Wl[(quad * 4 + 1) * 16 + l15]),
                         pkh2(Wl[(quad * 4 + 2) * 16 + l15], Wl[(quad * 4 + 3) * 16 + l15]));
  const f16x4 wwB = mkh4(pkh2(Ww[(quad * 4 + 0) * 16 + l15], Ww[(quad * 4 + 1) * 16 + l15]),
                         pkh2(Ww[(quad * 4 + 2) * 16 + l15], Ww[(quad * 4 + 3) * 16 + l15]));

  short8 qf0[4], qf1[4];
#pragma unroll
  for (int hh = 0; hh < 4; ++hh) {
    const unsigned short* qb =
        Qf + ((size_t)((b * N_H + w * 4 + hh) * SEQL) + qblk * 16 + l15) * D_K;
    qf0[hh] = *(const short8*)(qb + quad * 8);
    qf1[hh] = *(const short8*)(qb + 32 + quad * 8);
  }

  floatx4 oacc[4][4];
#pragma unroll
  for (int a = 0; a < 4; ++a)
#pragma unroll
    for (int d = 0; d < 4; ++d) oacc[a][d] = (floatx4){0.f, 0.f, 0.f, 0.f};

  __syncthreads();

  for (int rd = 0; rd < 2; ++rd) {
    const int k0 = ks * 128 + rd * 64;
    const float mreg = maskp[b * SEQL + k0 + w * 16 + l15];

#pragma unroll
    for (int kt = 0; kt < 4; ++kt) {
      floatx4 jc[4];
#pragma unroll
      for (int hh = 0; hh < 4; ++hh) {
        const unsigned short* kb =
            Kf + ((size_t)((b * N_H + w * 4 + hh) * SEQL) + k0 + kt * 16 + l15) * D_K;
        const short8 kf0 = *(const short8*)(kb + quad * 8);
        const short8 kf1 = *(const short8*)(kb + 32 + quad * 8);
        floatx4 c = (floatx4){0.f, 0.f, 0.f, 0.f};
        c = __builtin_amdgcn_mfma_f32_16x16x32_bf16(qf0[hh], kf0, c, 0, 0, 0);
        c = __builtin_amdgcn_mfma_f32_16x16x32_bf16(qf1[hh], kf1, c, 0, 0, 0);
        jc[hh] = c;
      }
#pragma unroll
      for (int r = 0; r < 4; ++r) {
        const int base = ((quad * 4 + r) * 64 + kt * 16 + l15) * 9 + w * 2;
        JtU[base + 0] = pkh2(jc[0][r], jc[1][r]);
        JtU[base + 1] = pkh2(jc[2][r], jc[3][r]);
      }
    }

    __syncthreads();

#pragma unroll 4
    for (int q = 0; q < 16; ++q) {
      const int jb = (q * 64 + w * 16 + l15) * 9 + quad * 2;
      const f16x4 bj = mkh4(JtU[jb], JtU[jb + 1]);
      floatx4 d1 = __builtin_amdgcn_mfma_f32_16x16x16f16(
          wlA, bj, (floatx4){0.f, 0.f, 0.f, 0.f}, 0, 0, 0);
      const floatx4 iq = *(const floatx4*)&invls[q][quad * 4];
      float p[4];
#pragma unroll
      for (int r = 0; r < 4; ++r) {
        const float e = fminf(fmaxf(d1[r] - mreg, -60.f), 60.f);
        p[r] = __expf(e) * iq[r];
      }
      const f16x4 ap = mkh4(pkh2(p[0], p[1]), pkh2(p[2], p[3]));
      floatx4 d2 = __builtin_amdgcn_mfma_f32_16x16x16f16(
          ap, wwB, (floatx4){0.f, 0.f, 0.f, 0.f}, 0, 0, 0);
      const int ub = (q * 64 + w * 16) * 9 + ((l15 + q) & 15) * 8 + quad * 2;
      *(uint2v*)&JtU[ub] = (uint2v){pkbf(d2[0], d2[1]), pkbf(d2[2], d2[3])};
    }

    __syncthreads();

    const unsigned short* JtS = (const unsigned short*)JtU;
#pragma unroll
    for (int tp = 0; tp < 2; ++tp) {
      const int kt_abs = ks * 128 + rd * 64 + tp * 32;
#pragma unroll
      for (int vv = 0; vv < 4; ++vv) {
        const int v = w * 4 + vv;
        const int wp = tp * 2 + (quad >> 1);
        const int so = (l15 * 64 + wp * 16) * 18 + ((v + l15) & 15) * 16 + (quad & 1) * 8;
        const short8 ufr = *(const short8*)&JtS[so];
#pragma unroll
        for (int dt = 0; dt < 4; ++dt) {
          const short8 vfr = *(const short8*)(Vf +
              ((size_t)((b * N_H + v) * D_K + dt * 16 + l15)) * SEQL + kt_abs + quad * 8);
          oacc[vv][dt] = __builtin_amdgcn_mfma_f32_16x16x32_bf16(ufr, vfr, oacc[vv][dt], 0, 0, 0);
        }
      }
    }

    __syncthreads();
  }

#pragma unroll
  for (int vv = 0; vv < 4; ++vv) {
    const int v = w * 4 + vv;
#pragma unroll
    for (int dt = 0; dt < 4; ++dt) {
      const int d = dt * 16 + l15;
#pragma unroll
      for (int r = 0; r < 4; ++r) {
        const int q = qblk * 16 + quad * 4 + r;
        Obp[(size_t)ks * BQJ + ((size_t)(b * SEQL + q)) * 1024 + d * 16 + v] = f2bf(oacc[vv][dt][r]);
      }
    }
  }
}

// ---------------------------------------------------------------------------
// K2s: Obsum = sum over nks Obp partials (legacy path only). grid(1024).
// ---------------------------------------------------------------------------
__global__ __launch_bounds__(256) void ath_osum(
    const unsigned short* __restrict__ Obp,
    unsigned short* __restrict__ Obsum, int nks)
{
  const size_t i = ((size_t)blockIdx.x * 256 + threadIdx.x) * 8;
  float a[8];
#pragma unroll
  for (int e = 0; e < 8; ++e) a[e] = 0.f;
  for (int ks = 0; ks < nks; ++ks) {
    const short8 v = *(const short8*)(Obp + (size_t)ks * BQJ + i);
#pragma unroll
    for (int e = 0; e < 8; ++e) a[e] += bf2f((unsigned short)v[e]);
  }
  short8 o;
#pragma unroll
  for (int e = 0; e < 8; ++e) o[e] = (short)f2bf(a[e]);
  *(short8*)(Obsum + i) = o;
}

// ---------------------------------------------------------------------------
// K3 (P path, fused osum): staging sums the KSO=4 bf16 partials in f32 then
// packs bf16 (bit-identical to osum->reload). fp32 out with inp residual.
// ---------------------------------------------------------------------------
__global__ __launch_bounds__(256) void ath_outf(
    const float* __restrict__ inp,
    const unsigned short* __restrict__ WoT,   // [co][j] bf16
    const unsigned short* __restrict__ Obp,   // KSO partials
    float* __restrict__ out)
{
  const int qblk = blockIdx.x;
  const int cblk = blockIdx.y;
  const int b    = blockIdx.z;
  const int tid = threadIdx.x;
  const int w = tid >> 6, lane = tid & 63;
  const int l15 = lane & 15, quad = lane >> 4;

  __shared__ __align__(16) unsigned short Os[64][40];
  __shared__ __align__(16) unsigned short Wt[64][40];

  floatx4 acc[4];
#pragma unroll
  for (int i = 0; i < 4; ++i) acc[i] = (floatx4){0.f, 0.f, 0.f, 0.f};

  const int srow = tid >> 2, sj8 = (tid & 3) * 8;

  for (int jc = 0; jc < 32; ++jc) {
    const int j0 = jc * 32;
    __syncthreads();
    {
      const size_t obase = ((size_t)(b * SEQL + qblk * 64 + srow)) * 1024 + j0 + sj8;
      short8 pv[KSO];
#pragma unroll
      for (int ksb = 0; ksb < KSO; ++ksb)
        pv[ksb] = *(const short8*)(Obp + (size_t)ksb * BQJ + obase);
      float a[8];
#pragma unroll
      for (int e = 0; e < 8; ++e) a[e] = 0.f;
#pragma unroll
      for (int ksb = 0; ksb < KSO; ++ksb)
#pragma unroll
        for (int e = 0; e < 8; ++e) a[e] += bf2f((unsigned short)pv[ksb][e]);
      short8 o;
#pragma unroll
      for (int e = 0; e < 8; ++e) o[e] = (short)f2bf(a[e]);
      *(short8*)&Os[srow][sj8] = o;
    }
    *(short8*)&Wt[srow][sj8] =
        *(const short8*)(WoT + ((size_t)(cblk * 64 + srow)) * 1024 + j0 + sj8);
    __syncthreads();
    const short8 a = *(const short8*)&Os[w * 16 + l15][quad * 8];
#pragma unroll
    for (int nt = 0; nt < 4; ++nt) {
      const short8 bb = *(const short8*)&Wt[nt * 16 + l15][quad * 8];
      acc[nt] = __builtin_amdgcn_mfma_f32_16x16x32_bf16(a, bb, acc[nt], 0, 0, 0);
    }
  }

#pragma unroll
  for (int nt = 0; nt < 4; ++nt) {
    const int co = cblk * 64 + nt * 16 + l15;
    const int qb = qblk * 64 + w * 16 + quad * 4;
    const float* ip = inp + ((size_t)(b * 512 + co)) * SEQL + qb;
    float* op = out + ((size_t)(b * 512 + co)) * SEQL + qb;
#pragma unroll
    for (int r = 0; r < 4; ++r) op[r] = acc[nt][r] + ip[r];
  }
}

// ---------------------------------------------------------------------------
// K3 (legacy): out from pre-summed Obsum.
// ---------------------------------------------------------------------------
__global__ __launch_bounds__(256) void ath_out(
    const float* __restrict__ inp,
    const unsigned short* __restrict__ WoT,   // [co][j] bf16
    const unsigned short* __restrict__ Ob,
    float* __restrict__ out)
{
  const int qblk = blockIdx.x;
  const int cblk = blockIdx.y;
  const int b    = blockIdx.z;
  const int tid = threadIdx.x;
  const int w = tid >> 6, lane = tid & 63;
  const int l15 = lane & 15, quad = lane >> 4;

  __shared__ __align__(16) unsigned short Os[64][40];
  __shared__ __align__(16) unsigned short Wt[64][40];

  floatx4 acc[4];
#pragma unroll
  for (int i = 0; i < 4; ++i) acc[i] = (floatx4){0.f, 0.f, 0.f, 0.f};

  const int srow = tid >> 2, sj8 = (tid & 3) * 8;

  for (int jc = 0; jc < 32; ++jc) {
    const int j0 = jc * 32;
    __syncthreads();
    *(short8*)&Os[srow][sj8] =
        *(const short8*)(Ob + ((size_t)(b * SEQL + qblk * 64 + srow)) * 1024 + j0 + sj8);
    *(short8*)&Wt[srow][sj8] =
        *(const short8*)(WoT + ((size_t)(cblk * 64 + srow)) * 1024 + j0 + sj8);
    __syncthreads();
    const short8 a = *(const short8*)&Os[w * 16 + l15][quad * 8];
#pragma unroll
    for (int nt = 0; nt < 4; ++nt) {
      const short8 bb = *(const short8*)&Wt[nt * 16 + l15][quad * 8];
      acc[nt] = __builtin_amdgcn_mfma_f32_16x16x32_bf16(a, bb, acc[nt], 0, 0, 0);
    }
  }

#pragma unroll
  for (int nt = 0; nt < 4; ++nt) {
    const int co = cblk * 64 + nt * 16 + l15;
    const int qb = qblk * 64 + w * 16 + quad * 4;
    const float* ip = inp + ((size_t)(b * 512 + co)) * SEQL + qb;
    float* op = out + ((size_t)(b * 512 + co)) * SEQL + qb;
#pragma unroll
    for (int r = 0; r < 4; ++r) op[r] = acc[nt][r] + ip[r];
  }
}

// ---------------------------------------------------------------------------
extern "C" void kernel_launch(void* const* d_in, const int* in_sizes, int n_in,
                              void* d_out, int out_size, void* d_ws, size_t ws_size,
                              hipStream_t stream) {
  (void)in_sizes; (void)n_in; (void)out_size;
  const float* inp   = (const float*)d_in[0];
  const float* maskp = (const float*)d_in[1];
  const float* Wq    = (const float*)d_in[2];
  const float* Wk    = (const float*)d_in[3];
  const float* Wv    = (const float*)d_in[4];
  const float* Aq    = (const float*)d_in[5];
  const float* Ak    = (const float*)d_in[6];
  const float* Av    = (const float*)d_in[7];
  const float* Wl    = (const float*)d_in[8];
  const float* Ww    = (const float*)d_in[9];
  const float* Wo    = (const float*)d_in[10];

  const size_t MB = 1u << 20;
  unsigned short* qkv   = (unsigned short*)d_ws;                       // [0,12) Q,K,V bf16
  unsigned short* Obsum = (unsigned short*)((char*)d_ws + 12 * MB);    // [12,16) legacy
  float*          invl  = (float*)((char*)d_ws + 16 * MB);             // 128 KB
  unsigned short* WoT   = (unsigned short*)((char*)d_ws + 17 * MB);    // [17,18)
  float*          lp    = (float*)((char*)d_ws + 18 * MB);             // [18,26) 64 slots
  unsigned short* WT    = (unsigned short*)((char*)d_ws + 26 * MB);    // [26,29)
  unsigned short* inpT  = (unsigned short*)((char*)d_ws + 29 * MB);    // [29,31)
  unsigned short* Obp   = (unsigned short*)((char*)d_ws + 18 * MB);    // [18,34)/[18,50) after linv
  unsigned short* Pws   = (unsigned short*)((char*)d_ws + 50 * MB);    // [50,114) P cache
  float* out = (float*)d_out;

  const bool useP = ws_size >= (size_t)114 * MB;

  ath_tr<<<dim3(32, 32, 6), 256, 0, stream>>>(inp, Wq, Wk, Wv, Wo, inpT, WT, WoT);
  ath_qkv<<<dim3(16, 16, 6), 256, 0, stream>>>(inpT, WT, Aq, Ak, Av, qkv);
  if (useP) {
    ath_lpartP<<<dim3(64, KSL, 2), 256, 0, stream>>>(maskp, Wl, qkv, lp, Pws);
    ath_linv<<<dim3(128), 256, 0, stream>>>(lp, invl);
    ath_opartP<<<dim3(64, KSO, 4), 256, 0, stream>>>(Pws, Ww, qkv, invl, Obp);
    ath_outf<<<dim3(16, 8, 2), 256, 0, stream>>>(inp, WoT, Obp, out);
  } else {
    ath_lpart<<<dim3(64, KSL, 2), 256, 0, stream>>>(maskp, Wl, qkv, lp);
    ath_linv<<<dim3(128), 256, 0, stream>>>(lp, invl);
    ath_opart<<<dim3(64, KSO_LEG, 2), 256, 0, stream>>>(maskp, Wl, Ww, qkv, invl, Obp);
    ath_osum<<<dim3(1024), 256, 0, stream>>>(Obp, Obsum, KSO_LEG);
    ath_out<<<dim3(16, 8, 2), 256, 0, stream>>>(inp, WoT, Obsum, out);
  }
}

// Round 15
// 244.495 us; speedup vs baseline: 1.0232x; 1.0232x over previous
//
#include <hip/hip_runtime.h>
#include <hip/hip_bf16.h>

// TalkingHeads: BS=2, C_IN=512, SEQ=1024, DK=DV=64, H=16. fp32 I/O.
// Round 27: recombination of best-measured pieces. opartP (256,3) + KSO=4
// d-split (r14: 52.5 us, VGPR 52, no spill) + separate osum/out epilogue
// (r13: fused staging-sum epilogue confirmed slower twice, r11/r14).
// No new variables. Everything else identical to r14.

#define B_S  2
#define C_INN 512
#define SEQL 1024
#define D_K  64
#define N_H  16
#define BQJ  (2 * 1024 * 1024)   // elements of one O partial [b][q][j]
#define KSL  16                  // lpart split (lp has KSL*4 per-wave slots)
#define KSO  4                   // opart split (P path)
#define KSO_LEG 8                // legacy fallback opart split

typedef __attribute__((ext_vector_type(4))) float floatx4;
typedef __attribute__((ext_vector_type(8))) short short8;
typedef __attribute__((ext_vector_type(2))) unsigned int uint2v;
typedef __fp16 h2raw __attribute__((ext_vector_type(2)));
typedef _Float16 f16x4 __attribute__((ext_vector_type(4)));

static __device__ __forceinline__ float bf2f(unsigned short u) {
  union { unsigned int i; float f; } x; x.i = ((unsigned int)u) << 16; return x.f;
}
static __device__ __forceinline__ unsigned short f2bf(float f) {
  union { float f; unsigned int i; } x; x.f = f;
  return (unsigned short)((x.i + 0x7fffu + ((x.i >> 16) & 1u)) >> 16);
}
static __device__ __forceinline__ unsigned int pkh2(float a, float b) {
  h2raw r = __builtin_amdgcn_cvt_pkrtz(a, b);
  union { h2raw h; unsigned int u; } x; x.h = r; return x.u;
}
static __device__ __forceinline__ unsigned int pkbf(float a, float b) {
  return (unsigned int)f2bf(a) | ((unsigned int)f2bf(b) << 16);
}
static __device__ __forceinline__ f16x4 mkh4(unsigned int a, unsigned int b) {
  union { unsigned int u[2]; f16x4 h; } x; x.u[0] = a; x.u[1] = b; return x.h;
}

// ---------------------------------------------------------------------------
// K0: batched transpose+convert. z: 0,1=inp b0/b1 (512x1024 -> [s][c]);
// 2,3,4=Wq/Wk/Wv (512x1024 -> [n][c]); 5=Wo (1024x512 -> [co][j]). bf16 out.
// ---------------------------------------------------------------------------
__global__ __launch_bounds__(256) void ath_tr(
    const float* __restrict__ inp, const float* __restrict__ Wq,
    const float* __restrict__ Wk,  const float* __restrict__ Wv,
    const float* __restrict__ Wo,
    unsigned short* __restrict__ inpT, unsigned short* __restrict__ WT,
    unsigned short* __restrict__ WoT)
{
  const int z = blockIdx.z;
  const float* src; unsigned short* dst; int R, C;
  if      (z == 0) { src = inp;              dst = inpT;                R = 512;  C = 1024; }
  else if (z == 1) { src = inp + 512 * 1024; dst = inpT + 1024 * 512;   R = 512;  C = 1024; }
  else if (z == 2) { src = Wq;               dst = WT;                  R = 512;  C = 1024; }
  else if (z == 3) { src = Wk;               dst = WT + 1024 * 512;     R = 512;  C = 1024; }
  else if (z == 4) { src = Wv;               dst = WT + 2 * 1024 * 512; R = 512;  C = 1024; }
  else             { src = Wo;               dst = WoT;                 R = 1024; C = 512;  }
  const int ct = blockIdx.x, rt = blockIdx.y;
  if (ct * 32 >= C || rt * 32 >= R) return;

  __shared__ float Ts[32][33];
  const int t = threadIdx.x;
  {
    const int r = t >> 3, c4 = (t & 7) * 4;
    const floatx4 g = *(const floatx4*)(src + (size_t)(rt * 32 + r) * C + ct * 32 + c4);
    Ts[r][c4 + 0] = g[0]; Ts[r][c4 + 1] = g[1];
    Ts[r][c4 + 2] = g[2]; Ts[r][c4 + 3] = g[3];
  }
  __syncthreads();
  {
    const int i = t >> 3, k4 = (t & 7) * 4;
    const unsigned int o0 = pkbf(Ts[k4 + 0][i], Ts[k4 + 1][i]);
    const unsigned int o1 = pkbf(Ts[k4 + 2][i], Ts[k4 + 3][i]);
    *(uint2v*)(dst + (size_t)(ct * 32 + i) * R + rt * 32 + k4) = (uint2v){o0, o1};
  }
}

// ---------------------------------------------------------------------------
// K1: QKV projection from pre-transposed bf16 inputs.
// Q,K -> [b][h][s][d] ; V -> [b][v][d][s]. Staging = b128 row copies.
// ---------------------------------------------------------------------------
__global__ __launch_bounds__(256) void ath_qkv(
    const unsigned short* __restrict__ inpT,  // [b][s][c]
    const unsigned short* __restrict__ WT,    // [p][n][c]
    const float* __restrict__ Aq,
    const float* __restrict__ Ak,
    const float* __restrict__ Av,
    unsigned short* __restrict__ ws)
{
  const int sblk = blockIdx.x;
  const int nblk = blockIdx.y;
  const int z = blockIdx.z;
  const int b = z / 3, p = z % 3;
  const float* Ap = (p == 0) ? Aq : ((p == 1) ? Ak : Av);
  const float sig = 1.0f / (1.0f + __expf(-Ap[0]));

  __shared__ __align__(16) unsigned short As[64][40];
  __shared__ __align__(16) unsigned short Bs[64][40];

  const int tid = threadIdx.x;
  const int w = tid >> 6, lane = tid & 63;
  const int l15 = lane & 15, quad = lane >> 4;
  const int srow = tid >> 2, sc8 = (tid & 3) * 8;

  floatx4 acc[4];
#pragma unroll
  for (int i = 0; i < 4; ++i) acc[i] = (floatx4){0.f, 0.f, 0.f, 0.f};

  for (int cc = 0; cc < 16; ++cc) {
    const int c0 = cc * 32;
    __syncthreads();
    *(short8*)&As[srow][sc8] =
        *(const short8*)(inpT + ((size_t)(b * 1024 + sblk * 64 + srow)) * 512 + c0 + sc8);
    *(short8*)&Bs[srow][sc8] =
        *(const short8*)(WT + ((size_t)(p * 1024 + nblk * 64 + srow)) * 512 + c0 + sc8);
    __syncthreads();
    const short8 a = *(const short8*)&As[w * 16 + l15][quad * 8];
#pragma unroll
    for (int nt = 0; nt < 4; ++nt) {
      const short8 bb = *(const short8*)&Bs[nt * 16 + l15][quad * 8];
      acc[nt] = __builtin_amdgcn_mfma_f32_16x16x32_bf16(a, bb, acc[nt], 0, 0, 0);
    }
  }

  unsigned short* out = ws + (size_t)p * ((size_t)B_S * N_H * SEQL * D_K);
#pragma unroll
  for (int nt = 0; nt < 4; ++nt) {
    const int h = l15;
    const int d = nblk * 4 + nt;
#pragma unroll
    for (int r = 0; r < 4; ++r) {
      const int s = sblk * 64 + w * 16 + quad * 4 + r;
      const float vout = acc[nt][r] * sig;
      if (p == 2) out[((size_t)((b * N_H + h) * D_K + d)) * SEQL + s] = f2bf(vout);
      else        out[((size_t)((b * N_H + h) * SEQL + s)) * D_K + d] = f2bf(vout);
    }
  }
}

// ---------------------------------------------------------------------------
// K2a (P path): partial l + P store; proven (256,3).
// ---------------------------------------------------------------------------
__global__ __launch_bounds__(256, 3) void ath_lpartP(
    const float* __restrict__ maskp,
    const float* __restrict__ Wl,
    const unsigned short* __restrict__ qkv,
    float* __restrict__ lp,
    unsigned short* __restrict__ Pws)
{
  const int qblk = blockIdx.x;
  const int ks   = blockIdx.y;
  const int b    = blockIdx.z;
  const int tid = threadIdx.x;
  const int w = tid >> 6, lane = tid & 63;
  const int l15 = lane & 15, quad = lane >> 4;

  const unsigned short* Qf = qkv;
  const unsigned short* Kf = qkv + (size_t)B_S * N_H * SEQL * D_K;

  __shared__ unsigned int JtU[9216];  // [q16*64 + k][9] f16 pairs, 36 KB

  const f16x4 wlA = mkh4(pkh2(Wl[(quad * 4 + 0) * 16 + l15], Wl[(quad * 4 + 1) * 16 + l15]),
                         pkh2(Wl[(quad * 4 + 2) * 16 + l15], Wl[(quad * 4 + 3) * 16 + l15]));
  const f16x4 idB = mkh4(pkh2((quad * 4 + 0 == l15) ? 1.f : 0.f, (quad * 4 + 1 == l15) ? 1.f : 0.f),
                         pkh2((quad * 4 + 2 == l15) ? 1.f : 0.f, (quad * 4 + 3 == l15) ? 1.f : 0.f));
  const unsigned int ONE2 = 0x3C003C00u;
  const f16x4 onesB = mkh4(ONE2, ONE2);
  const f16x4 zeroB = mkh4(0u, 0u);

  const float mreg = maskp[b * SEQL + ks * 64 + w * 16 + l15];  // mask[k=l15]
  const int k0 = ks * 64;
  const int kabs = k0 + w * 16 + l15;

  short8 qf0[4], qf1[4];
#pragma unroll
  for (int hh = 0; hh < 4; ++hh) {
    const unsigned short* qb =
        Qf + ((size_t)((b * N_H + w * 4 + hh) * SEQL) + qblk * 16 + l15) * D_K;
    qf0[hh] = *(const short8*)(qb + quad * 8);
    qf1[hh] = *(const short8*)(qb + 32 + quad * 8);
  }

#pragma unroll
  for (int kt = 0; kt < 4; ++kt) {
    floatx4 jc[4];
#pragma unroll
    for (int hh = 0; hh < 4; ++hh) {
      const unsigned short* kb =
          Kf + ((size_t)((b * N_H + w * 4 + hh) * SEQL) + k0 + kt * 16 + l15) * D_K;
      const short8 kf0 = *(const short8*)(kb + quad * 8);
      const short8 kf1 = *(const short8*)(kb + 32 + quad * 8);
      floatx4 c = (floatx4){0.f, 0.f, 0.f, 0.f};
      c = __builtin_amdgcn_mfma_f32_16x16x32_bf16(qf0[hh], kf0, c, 0, 0, 0);
      c = __builtin_amdgcn_mfma_f32_16x16x32_bf16(qf1[hh], kf1, c, 0, 0, 0);
      jc[hh] = c;
    }
#pragma unroll
    for (int r = 0; r < 4; ++r) {
      const int base = ((quad * 4 + r) * 64 + kt * 16 + l15) * 9 + w * 2;
      JtU[base + 0] = pkh2(jc[0][r], jc[1][r]);
      JtU[base + 1] = pkh2(jc[2][r], jc[3][r]);
    }
  }

  __syncthreads();  // JtU complete (all waves' h-pairs)

  unsigned int* Pu = (unsigned int*)Pws;
  floatx4 dl0 = (floatx4){0.f, 0.f, 0.f, 0.f};
  floatx4 dl1 = (floatx4){0.f, 0.f, 0.f, 0.f};
#pragma unroll 4
  for (int q = 0; q < 16; ++q) {
    const int jb = (q * 64 + w * 16 + l15) * 9 + quad * 2;   // B[h=quad*4+j][k=l15]
    const f16x4 bj = mkh4(JtU[jb], JtU[jb + 1]);
    floatx4 d1 = __builtin_amdgcn_mfma_f32_16x16x16f16(
        wlA, bj, (floatx4){0.f, 0.f, 0.f, 0.f}, 0, 0, 0);  // (g rows, k cols)
    float p[4];
#pragma unroll
    for (int r = 0; r < 4; ++r) {
      const float e = fminf(fmaxf(d1[r] - mreg, -60.f), 60.f);
      p[r] = __expf(e);
    }
    const unsigned int u0 = pkh2(p[0], p[1]);
    const unsigned int u1 = pkh2(p[2], p[3]);
    const size_t pidx =
        ((size_t)(b * 1024 + qblk * 16 + q) * 1024 + kabs) * 8 + quad * 2;
    *(uint2v*)&Pu[pidx] = (uint2v){u0, u1};

    const f16x4 ap = mkh4(u0, u1);
    floatx4 dt = __builtin_amdgcn_mfma_f32_16x16x16f16(
        ap, idB, (floatx4){0.f, 0.f, 0.f, 0.f}, 0, 0, 0);   // (k rows, g cols)
    const f16x4 a2 = mkh4(pkh2(dt[0], dt[1]), pkh2(dt[2], dt[3]));  // A[g][k]
    const f16x4 eq = (l15 == q) ? onesB : zeroB;  // B[k][col]=delta(col,q)
    if (q & 1) dl1 = __builtin_amdgcn_mfma_f32_16x16x16f16(a2, eq, dl1, 0, 0, 0);
    else       dl0 = __builtin_amdgcn_mfma_f32_16x16x16f16(a2, eq, dl0, 0, 0, 0);
  }
  const floatx4 dl = dl0 + dl1;

  *(floatx4*)(lp + ((size_t)((ks * 4 + w) * 2 + b)) * 16384 +
              (size_t)(qblk * 16 + l15) * 16 + quad * 4) = dl;
}

// ---------------------------------------------------------------------------
// K2a (fallback): legacy lpart, identical to r18.
// ---------------------------------------------------------------------------
__global__ __launch_bounds__(256, 3) void ath_lpart(
    const float* __restrict__ maskp,
    const float* __restrict__ Wl,
    const unsigned short* __restrict__ qkv,
    float* __restrict__ lp)
{
  const int qblk = blockIdx.x;
  const int ks   = blockIdx.y;
  const int b    = blockIdx.z;
  const int tid = threadIdx.x;
  const int w = tid >> 6, lane = tid & 63;
  const int l15 = lane & 15, quad = lane >> 4;

  const unsigned short* Qf = qkv;
  const unsigned short* Kf = qkv + (size_t)B_S * N_H * SEQL * D_K;

  __shared__ unsigned int JtU[9216];

  const f16x4 wlA = mkh4(pkh2(Wl[(quad * 4 + 0) * 16 + l15], Wl[(quad * 4 + 1) * 16 + l15]),
                         pkh2(Wl[(quad * 4 + 2) * 16 + l15], Wl[(quad * 4 + 3) * 16 + l15]));
  const f16x4 idB = mkh4(pkh2((quad * 4 + 0 == l15) ? 1.f : 0.f, (quad * 4 + 1 == l15) ? 1.f : 0.f),
                         pkh2((quad * 4 + 2 == l15) ? 1.f : 0.f, (quad * 4 + 3 == l15) ? 1.f : 0.f));
  const unsigned int ONE2 = 0x3C003C00u;
  const f16x4 onesB = mkh4(ONE2, ONE2);
  const f16x4 zeroB = mkh4(0u, 0u);

  const float mreg = maskp[b * SEQL + ks * 64 + w * 16 + l15];
  const int k0 = ks * 64;

  short8 qf0[4], qf1[4];
#pragma unroll
  for (int hh = 0; hh < 4; ++hh) {
    const unsigned short* qb =
        Qf + ((size_t)((b * N_H + w * 4 + hh) * SEQL) + qblk * 16 + l15) * D_K;
    qf0[hh] = *(const short8*)(qb + quad * 8);
    qf1[hh] = *(const short8*)(qb + 32 + quad * 8);
  }

#pragma unroll
  for (int kt = 0; kt < 4; ++kt) {
    floatx4 jc[4];
#pragma unroll
    for (int hh = 0; hh < 4; ++hh) {
      const unsigned short* kb =
          Kf + ((size_t)((b * N_H + w * 4 + hh) * SEQL) + k0 + kt * 16 + l15) * D_K;
      const short8 kf0 = *(const short8*)(kb + quad * 8);
      const short8 kf1 = *(const short8*)(kb + 32 + quad * 8);
      floatx4 c = (floatx4){0.f, 0.f, 0.f, 0.f};
      c = __builtin_amdgcn_mfma_f32_16x16x32_bf16(qf0[hh], kf0, c, 0, 0, 0);
      c = __builtin_amdgcn_mfma_f32_16x16x32_bf16(qf1[hh], kf1, c, 0, 0, 0);
      jc[hh] = c;
    }
#pragma unroll
    for (int r = 0; r < 4; ++r) {
      const int base = ((quad * 4 + r) * 64 + kt * 16 + l15) * 9 + w * 2;
      JtU[base + 0] = pkh2(jc[0][r], jc[1][r]);
      JtU[base + 1] = pkh2(jc[2][r], jc[3][r]);
    }
  }

  __syncthreads();

  floatx4 dl0 = (floatx4){0.f, 0.f, 0.f, 0.f};
  floatx4 dl1 = (floatx4){0.f, 0.f, 0.f, 0.f};
#pragma unroll 4
  for (int q = 0; q < 16; ++q) {
    const int jb = (q * 64 + w * 16 + l15) * 9 + quad * 2;
    const f16x4 bj = mkh4(JtU[jb], JtU[jb + 1]);
    floatx4 d1 = __builtin_amdgcn_mfma_f32_16x16x16f16(
        wlA, bj, (floatx4){0.f, 0.f, 0.f, 0.f}, 0, 0, 0);
    float p[4];
#pragma unroll
    for (int r = 0; r < 4; ++r) {
      const float e = fminf(fmaxf(d1[r] - mreg, -60.f), 60.f);
      p[r] = __expf(e);
    }
    const f16x4 ap = mkh4(pkh2(p[0], p[1]), pkh2(p[2], p[3]));
    floatx4 dt = __builtin_amdgcn_mfma_f32_16x16x16f16(
        ap, idB, (floatx4){0.f, 0.f, 0.f, 0.f}, 0, 0, 0);
    const f16x4 a2 = mkh4(pkh2(dt[0], dt[1]), pkh2(dt[2], dt[3]));
    const f16x4 eq = (l15 == q) ? onesB : zeroB;
    if (q & 1) dl1 = __builtin_amdgcn_mfma_f32_16x16x16f16(a2, eq, dl1, 0, 0, 0);
    else       dl0 = __builtin_amdgcn_mfma_f32_16x16x16f16(a2, eq, dl0, 0, 0, 0);
  }
  const floatx4 dl = dl0 + dl1;

  *(floatx4*)(lp + ((size_t)((ks * 4 + w) * 2 + b)) * 16384 +
              (size_t)(qblk * 16 + l15) * 16 + quad * 4) = dl;
}

// ---------------------------------------------------------------------------
// K2r: invl = 1 / sum over KSL*4 per-wave slots. grid(128, 256 thr).
// ---------------------------------------------------------------------------
__global__ __launch_bounds__(256) void ath_linv(
    const float* __restrict__ lp, float* __restrict__ invl)
{
  const int t = blockIdx.x * 256 + threadIdx.x;
  const int b = t >> 14, rem = t & 16383;
  float s = 0.f;
#pragma unroll
  for (int sl = 0; sl < KSL * 4; ++sl) s += lp[(size_t)(sl * 2 + b) * 16384 + rem];
  invl[t] = 1.0f / fmaxf(s, 1e-37f);
}

// ---------------------------------------------------------------------------
// K2b (P path): d-split partial O, KSO=4 (k-256/block over 4 rds).
// grid(64, 4, 4: z=b*2+dh) = 1024 blocks; (256,3) = best measured config
// (r14: 52.5 us, VGPR 52, FETCH 49 / WRITE 16 MB).
// ---------------------------------------------------------------------------
__global__ __launch_bounds__(256, 3) void ath_opartP(
    const unsigned short* __restrict__ Pws,   // [b][q][k][g16] f16 unnorm
    const float* __restrict__ Ww,
    const unsigned short* __restrict__ qkv,
    const float* __restrict__ invl,
    unsigned short* __restrict__ Obp)
{
  const int qblk = blockIdx.x;
  const int ks   = blockIdx.y;
  const int z    = blockIdx.z;          // b*2 + dh
  const int b = z >> 1, dh = z & 1;
  const int tid = threadIdx.x;
  const int w = tid >> 6, lane = tid & 63;
  const int l15 = lane & 15, quad = lane >> 4;

  const unsigned short* Vf = qkv + 2 * (size_t)B_S * N_H * SEQL * D_K;

  __shared__ __align__(16) unsigned short Us[16 * 16 * 64];  // 32 KB, swizzled
  __shared__ float invls[16][16];

  invls[tid >> 4][tid & 15] =
      invl[(size_t)b * 16384 + (qblk * 16 + (tid >> 4)) * 16 + (tid & 15)];

  const f16x4 wwB = mkh4(pkh2(Ww[(quad * 4 + 0) * 16 + l15], Ww[(quad * 4 + 1) * 16 + l15]),
                         pkh2(Ww[(quad * 4 + 2) * 16 + l15], Ww[(quad * 4 + 3) * 16 + l15]));

  floatx4 oacc[4][2];
#pragma unroll
  for (int a = 0; a < 4; ++a)
#pragma unroll
    for (int d = 0; d < 2; ++d) oacc[a][d] = (floatx4){0.f, 0.f, 0.f, 0.f};

  const unsigned int* Pu = (const unsigned int*)Pws;

  __syncthreads();  // invls visible

  for (int rd = 0; rd < 4; ++rd) {
    const int kabs = ks * 256 + rd * 64 + w * 16 + l15;

    // ---- mix: read P (batches of 8 q), x inv, U-mfma, swizzled Us write ----
#pragma unroll
    for (int qh = 0; qh < 2; ++qh) {
      uint2v pv[8];
#pragma unroll
      for (int qq = 0; qq < 8; ++qq) {
        const size_t pidx =
            ((size_t)(b * 1024 + qblk * 16 + qh * 8 + qq) * 1024 + kabs) * 8 + quad * 2;
        pv[qq] = *(const uint2v*)&Pu[pidx];
      }
#pragma unroll
      for (int qq = 0; qq < 8; ++qq) {
        const int q = qh * 8 + qq;
        const floatx4 iq = *(const floatx4*)&invls[q][quad * 4];
        union { unsigned int u; _Float16 h[2]; } z0, z1;
        z0.u = pv[qq][0]; z1.u = pv[qq][1];
        const f16x4 ap = mkh4(pkh2((float)z0.h[0] * iq[0], (float)z0.h[1] * iq[1]),
                              pkh2((float)z1.h[0] * iq[2], (float)z1.h[1] * iq[3]));
        floatx4 d2 = __builtin_amdgcn_mfma_f32_16x16x16f16(
            ap, wwB, (floatx4){0.f, 0.f, 0.f, 0.f}, 0, 0, 0);  // U: k rows, v=l15
        const int row = l15 * 16 + q;
        const int ch = (w * 2 + (quad >> 1)) ^ ((l15 ^ q) & 7);
        *(uint2v*)&Us[row * 64 + ch * 8 + (quad & 1) * 4] =
            (uint2v){pkbf(d2[0], d2[1]), pkbf(d2[2], d2[3])};
      }
    }

    __syncthreads();  // all waves' Us slices ready

    // ---- V-phase: wave w -> v = 4w..4w+3; d-tiles dh*2+dt (dt 0..1) ----
#pragma unroll
    for (int tp = 0; tp < 2; ++tp) {
      const int kt_abs = ks * 256 + rd * 64 + tp * 32;
#pragma unroll
      for (int vv = 0; vv < 4; ++vv) {
        const int v = w * 4 + vv;
        const int ch = (tp * 4 + quad) ^ ((v ^ l15) & 7);
        const short8 ufr = *(const short8*)&Us[(v * 16 + l15) * 64 + ch * 8];
#pragma unroll
        for (int dt = 0; dt < 2; ++dt) {
          const int dtile = dh * 2 + dt;
          const short8 vfr = *(const short8*)(Vf +
              ((size_t)((b * N_H + v) * D_K + dtile * 16 + l15)) * SEQL + kt_abs + quad * 8);
          oacc[vv][dt] = __builtin_amdgcn_mfma_f32_16x16x32_bf16(ufr, vfr, oacc[vv][dt], 0, 0, 0);
        }
      }
    }

    __syncthreads();  // Us free for next rd
  }

#pragma unroll
  for (int vv = 0; vv < 4; ++vv) {
    const int v = w * 4 + vv;
#pragma unroll
    for (int dt = 0; dt < 2; ++dt) {
      const int d = (dh * 2 + dt) * 16 + l15;
#pragma unroll
      for (int r = 0; r < 4; ++r) {
        const int q = qblk * 16 + quad * 4 + r;
        Obp[(size_t)ks * BQJ + ((size_t)(b * SEQL + q)) * 1024 + d * 16 + v] = f2bf(oacc[vv][dt][r]);
      }
    }
  }
}

// ---------------------------------------------------------------------------
// K2b (fallback): legacy opart, identical to r18 (KSO_LEG=8 split).
// ---------------------------------------------------------------------------
__global__ __launch_bounds__(256, 2) void ath_opart(
    const float* __restrict__ maskp,
    const float* __restrict__ Wl,
    const float* __restrict__ Ww,
    const unsigned short* __restrict__ qkv,
    const float* __restrict__ invl,
    unsigned short* __restrict__ Obp)
{
  const int qblk = blockIdx.x;
  const int ks   = blockIdx.y;
  const int b    = blockIdx.z;
  const int tid = threadIdx.x;
  const int w = tid >> 6, lane = tid & 63;
  const int l15 = lane & 15, quad = lane >> 4;

  const unsigned short* Qf = qkv;
  const unsigned short* Kf = qkv + (size_t)B_S * N_H * SEQL * D_K;
  const unsigned short* Vf = qkv + 2 * (size_t)B_S * N_H * SEQL * D_K;

  __shared__ unsigned int JtU[9216];
  __shared__ float invls[16][16];

  invls[tid >> 4][tid & 15] =
      invl[(size_t)b * 16384 + (qblk * 16 + (tid >> 4)) * 16 + (tid & 15)];

  const f16x4 wlA = mkh4(pkh2(Wl[(quad * 4 + 0) * 16 + l15], Wl[(quad * 4 + 1) * 16 + l15]),
                         pkh2(Wl[(quad * 4 + 2) * 16 + l15], Wl[(quad * 4 + 3) * 16 + l15]));
  const f16x4 wwB = mkh4(pkh2(Ww[(quad * 4 + 0) * 16 + l15], Ww[(quad * 4 + 1) * 16 + l15]),
                         pkh2(Ww[(quad * 4 + 2) * 16 + l15], Ww[(quad * 4 + 3) * 16 + l15]));

  short8 qf0[4], qf1[4];
#pragma unroll
  for (int hh = 0; hh < 4; ++hh) {
    const unsigned short* qb =
        Qf + ((size_t)((b * N_H + w * 4 + hh) * SEQL) + qblk * 16 + l15) * D_K;
    qf0[hh] = *(const short8*)(qb + quad * 8);
    qf1[hh] = *(const short8*)(qb + 32 + quad * 8);
  }

  floatx4 oacc[4][4];
#pragma unroll
  for (int a = 0; a < 4; ++a)
#pragma unroll
    for (int d = 0; d < 4; ++d) oacc[a][d] = (floatx4){0.f, 0.f, 0.f, 0.f};

  __syncthreads();

  for (int rd = 0; rd < 2; ++rd) {
    const int k0 = ks * 128 + rd * 64;
    const float mreg = maskp[b * SEQL + k0 + w * 16 + l15];

#pragma unroll
    for (int kt = 0; kt < 4; ++kt) {
      floatx4 jc[4];
#pragma unroll
      for (int hh = 0; hh < 4; ++hh) {
        const unsigned short* kb =
            Kf + ((size_t)((b * N_H + w * 4 + hh) * SEQL) + k0 + kt * 16 + l15) * D_K;
        const short8 kf0 = *(const short8*)(kb + quad * 8);
        const short8 kf1 = *(const short8*)(kb + 32 + quad * 8);
        floatx4 c = (floatx4){0.f, 0.f, 0.f, 0.f};
        c = __builtin_amdgcn_mfma_f32_16x16x32_bf16(qf0[hh], kf0, c, 0, 0, 0);
        c = __builtin_amdgcn_mfma_f32_16x16x32_bf16(qf1[hh], kf1, c, 0, 0, 0);
        jc[hh] = c;
      }
#pragma unroll
      for (int r = 0; r < 4; ++r) {
        const int base = ((quad * 4 + r) * 64 + kt * 16 + l15) * 9 + w * 2;
        JtU[base + 0] = pkh2(jc[0][r], jc[1][r]);
        JtU[base + 1] = pkh2(jc[2][r], jc[3][r]);
      }
    }

    __syncthreads();

#pragma unroll 4
    for (int q = 0; q < 16; ++q) {
      const int jb = (q * 64 + w * 16 + l15) * 9 + quad * 2;
      const f16x4 bj = mkh4(JtU[jb], JtU[jb + 1]);
      floatx4 d1 = __builtin_amdgcn_mfma_f32_16x16x16f16(
          wlA, bj, (floatx4){0.f, 0.f, 0.f, 0.f}, 0, 0, 0);
      const floatx4 iq = *(const floatx4*)&invls[q][quad * 4];
      float p[4];
#pragma unroll
      for (int r = 0; r < 4; ++r) {
        const float e = fminf(fmaxf(d1[r] - mreg, -60.f), 60.f);
        p[r] = __expf(e) * iq[r];
      }
      const f16x4 ap = mkh4(pkh2(p[0], p[1]), pkh2(p[2], p[3]));
      floatx4 d2 = __builtin_amdgcn_mfma_f32_16x16x16f16(
          ap, wwB, (floatx4){0.f, 0.f, 0.f, 0.f}, 0, 0, 0);
      const int ub = (q * 64 + w * 16) * 9 + ((l15 + q) & 15) * 8 + quad * 2;
      *(uint2v*)&JtU[ub] = (uint2v){pkbf(d2[0], d2[1]), pkbf(d2[2], d2[3])};
    }

    __syncthreads();

    const unsigned short* JtS = (const unsigned short*)JtU;
#pragma unroll
    for (int tp = 0; tp < 2; ++tp) {
      const int kt_abs = ks * 128 + rd * 64 + tp * 32;
#pragma unroll
      for (int vv = 0; vv < 4; ++vv) {
        const int v = w * 4 + vv;
        const int wp = tp * 2 + (quad >> 1);
        const int so = (l15 * 64 + wp * 16) * 18 + ((v + l15) & 15) * 16 + (quad & 1) * 8;
        const short8 ufr = *(const short8*)&JtS[so];
#pragma unroll
        for (int dt = 0; dt < 4; ++dt) {
          const short8 vfr = *(const short8*)(Vf +
              ((size_t)((b * N_H + v) * D_K + dt * 16 + l15)) * SEQL + kt_abs + quad * 8);
          oacc[vv][dt] = __builtin_amdgcn_mfma_f32_16x16x32_bf16(ufr, vfr, oacc[vv][dt], 0, 0, 0);
        }
      }
    }

    __syncthreads();
  }

#pragma unroll
  for (int vv = 0; vv < 4; ++vv) {
    const int v = w * 4 + vv;
#pragma unroll
    for (int dt = 0; dt < 4; ++dt) {
      const int d = dt * 16 + l15;
#pragma unroll
      for (int r = 0; r < 4; ++r) {
        const int q = qblk * 16 + quad * 4 + r;
        Obp[(size_t)ks * BQJ + ((size_t)(b * SEQL + q)) * 1024 + d * 16 + v] = f2bf(oacc[vv][dt][r]);
      }
    }
  }
}

// ---------------------------------------------------------------------------
// K2s: Obsum = sum over nks Obp partials. grid(1024, 256 thr).
// ---------------------------------------------------------------------------
__global__ __launch_bounds__(256) void ath_osum(
    const unsigned short* __restrict__ Obp,
    unsigned short* __restrict__ Obsum, int nks)
{
  const size_t i = ((size_t)blockIdx.x * 256 + threadIdx.x) * 8;
  float a[8];
#pragma unroll
  for (int e = 0; e < 8; ++e) a[e] = 0.f;
  for (int ks = 0; ks < nks; ++ks) {
    const short8 v = *(const short8*)(Obp + (size_t)ks * BQJ + i);
#pragma unroll
    for (int e = 0; e < 8; ++e) a[e] += bf2f((unsigned short)v[e]);
  }
  short8 o;
#pragma unroll
  for (int e = 0; e < 8; ++e) o[e] = (short)f2bf(a[e]);
  *(short8*)(Obsum + i) = o;
}

// ---------------------------------------------------------------------------
// K3: out[b][co][q] = inp + sum_j Obsum[b][q][j] * WoT[co][j]. fp32 out.
// ---------------------------------------------------------------------------
__global__ __launch_bounds__(256) void ath_out(
    const float* __restrict__ inp,
    const unsigned short* __restrict__ WoT,   // [co][j] bf16
    const unsigned short* __restrict__ Ob,
    float* __restrict__ out)
{
  const int qblk = blockIdx.x;
  const int cblk = blockIdx.y;
  const int b    = blockIdx.z;
  const int tid = threadIdx.x;
  const int w = tid >> 6, lane = tid & 63;
  const int l15 = lane & 15, quad = lane >> 4;

  __shared__ __align__(16) unsigned short Os[64][40];
  __shared__ __align__(16) unsigned short Wt[64][40];

  floatx4 acc[4];
#pragma unroll
  for (int i = 0; i < 4; ++i) acc[i] = (floatx4){0.f, 0.f, 0.f, 0.f};

  const int srow = tid >> 2, sj8 = (tid & 3) * 8;

  for (int jc = 0; jc < 32; ++jc) {
    const int j0 = jc * 32;
    __syncthreads();
    *(short8*)&Os[srow][sj8] =
        *(const short8*)(Ob + ((size_t)(b * SEQL + qblk * 64 + srow)) * 1024 + j0 + sj8);
    *(short8*)&Wt[srow][sj8] =
        *(const short8*)(WoT + ((size_t)(cblk * 64 + srow)) * 1024 + j0 + sj8);
    __syncthreads();
    const short8 a = *(const short8*)&Os[w * 16 + l15][quad * 8];
#pragma unroll
    for (int nt = 0; nt < 4; ++nt) {
      const short8 bb = *(const short8*)&Wt[nt * 16 + l15][quad * 8];
      acc[nt] = __builtin_amdgcn_mfma_f32_16x16x32_bf16(a, bb, acc[nt], 0, 0, 0);
    }
  }

#pragma unroll
  for (int nt = 0; nt < 4; ++nt) {
    const int co = cblk * 64 + nt * 16 + l15;
    const int qb = qblk * 64 + w * 16 + quad * 4;
    const float* ip = inp + ((size_t)(b * 512 + co)) * SEQL + qb;
    float* op = out + ((size_t)(b * 512 + co)) * SEQL + qb;
#pragma unroll
    for (int r = 0; r < 4; ++r) op[r] = acc[nt][r] + ip[r];
  }
}

// ---------------------------------------------------------------------------
extern "C" void kernel_launch(void* const* d_in, const int* in_sizes, int n_in,
                              void* d_out, int out_size, void* d_ws, size_t ws_size,
                              hipStream_t stream) {
  (void)in_sizes; (void)n_in; (void)out_size;
  const float* inp   = (const float*)d_in[0];
  const float* maskp = (const float*)d_in[1];
  const float* Wq    = (const float*)d_in[2];
  const float* Wk    = (const float*)d_in[3];
  const float* Wv    = (const float*)d_in[4];
  const float* Aq    = (const float*)d_in[5];
  const float* Ak    = (const float*)d_in[6];
  const float* Av    = (const float*)d_in[7];
  const float* Wl    = (const float*)d_in[8];
  const float* Ww    = (const float*)d_in[9];
  const float* Wo    = (const float*)d_in[10];

  const size_t MB = 1u << 20;
  unsigned short* qkv   = (unsigned short*)d_ws;                       // [0,12) Q,K,V bf16
  unsigned short* Obsum = (unsigned short*)((char*)d_ws + 12 * MB);    // [12,16)
  float*          invl  = (float*)((char*)d_ws + 16 * MB);             // 128 KB
  unsigned short* WoT   = (unsigned short*)((char*)d_ws + 17 * MB);    // [17,18)
  float*          lp    = (float*)((char*)d_ws + 18 * MB);             // [18,26) 64 slots
  unsigned short* WT    = (unsigned short*)((char*)d_ws + 26 * MB);    // [26,29)
  unsigned short* inpT  = (unsigned short*)((char*)d_ws + 29 * MB);    // [29,31)
  unsigned short* Obp   = (unsigned short*)((char*)d_ws + 18 * MB);    // [18,34)/[18,50) after linv
  unsigned short* Pws   = (unsigned short*)((char*)d_ws + 50 * MB);    // [50,114) P cache
  float* out = (float*)d_out;

  const bool useP = ws_size >= (size_t)114 * MB;

  ath_tr<<<dim3(32, 32, 6), 256, 0, stream>>>(inp, Wq, Wk, Wv, Wo, inpT, WT, WoT);
  ath_qkv<<<dim3(16, 16, 6), 256, 0, stream>>>(inpT, WT, Aq, Ak, Av, qkv);
  if (useP) {
    ath_lpartP<<<dim3(64, KSL, 2), 256, 0, stream>>>(maskp, Wl, qkv, lp, Pws);
    ath_linv<<<dim3(128), 256, 0, stream>>>(lp, invl);
    ath_opartP<<<dim3(64, KSO, 4), 256, 0, stream>>>(Pws, Ww, qkv, invl, Obp);
    ath_osum<<<dim3(1024), 256, 0, stream>>>(Obp, Obsum, KSO);
  } else {
    ath_lpart<<<dim3(64, KSL, 2), 256, 0, stream>>>(maskp, Wl, qkv, lp);
    ath_linv<<<dim3(128), 256, 0, stream>>>(lp, invl);
    ath_opart<<<dim3(64, KSO_LEG, 2), 256, 0, stream>>>(maskp, Wl, Ww, qkv, invl, Obp);
    ath_osum<<<dim3(1024), 256, 0, stream>>>(Obp, Obsum, KSO_LEG);
  }
  ath_out<<<dim3(16, 8, 2), 256, 0, stream>>>(inp, WoT, Obsum, out);
}

// Round 16
// 232.505 us; speedup vs baseline: 1.0760x; 1.0516x over previous
//
#include <hip/hip_runtime.h>
#include <hip/hip_bf16.h>

// TalkingHeads: BS=2, C_IN=512, SEQ=1024, DK=DV=64, H=16. fp32 I/O.
// Round 28: lpartP KSL 16->8, 2 k-chunks per block. Q frags (resident VGPR)
// amortize over 2x k-range: Q traffic 64->32 MB, grid 2048->1024 blocks
// (2.67->1.33 dispatch waves at 3/CU), per-block setup halved, dl accumulated
// across chunks -> lp slots 64->32, linv work halved. Chunk body = proven
// r15 code + one barrier between mix and next chunk's J (JtU reuse hazard).
// opartP/osum/out = r15's best config (opartP variance r14 vs r15 at same
// binary shows +-5us noise; config mapped out). Legacy fallback unchanged.

#define B_S  2
#define C_INN 512
#define SEQL 1024
#define D_K  64
#define N_H  16
#define BQJ  (2 * 1024 * 1024)   // elements of one O partial [b][q][j]
#define KSL  16                  // legacy lpart split
#define KSL2 8                   // P-path lpart split (2 chunks of 64 k each)
#define KSO  4                   // opart split (P path)
#define KSO_LEG 8                // legacy fallback opart split

typedef __attribute__((ext_vector_type(4))) float floatx4;
typedef __attribute__((ext_vector_type(8))) short short8;
typedef __attribute__((ext_vector_type(2))) unsigned int uint2v;
typedef __fp16 h2raw __attribute__((ext_vector_type(2)));
typedef _Float16 f16x4 __attribute__((ext_vector_type(4)));

static __device__ __forceinline__ float bf2f(unsigned short u) {
  union { unsigned int i; float f; } x; x.i = ((unsigned int)u) << 16; return x.f;
}
static __device__ __forceinline__ unsigned short f2bf(float f) {
  union { float f; unsigned int i; } x; x.f = f;
  return (unsigned short)((x.i + 0x7fffu + ((x.i >> 16) & 1u)) >> 16);
}
static __device__ __forceinline__ unsigned int pkh2(float a, float b) {
  h2raw r = __builtin_amdgcn_cvt_pkrtz(a, b);
  union { h2raw h; unsigned int u; } x; x.h = r; return x.u;
}
static __device__ __forceinline__ unsigned int pkbf(float a, float b) {
  return (unsigned int)f2bf(a) | ((unsigned int)f2bf(b) << 16);
}
static __device__ __forceinline__ f16x4 mkh4(unsigned int a, unsigned int b) {
  union { unsigned int u[2]; f16x4 h; } x; x.u[0] = a; x.u[1] = b; return x.h;
}

// ---------------------------------------------------------------------------
// K0: batched transpose+convert. z: 0,1=inp b0/b1 (512x1024 -> [s][c]);
// 2,3,4=Wq/Wk/Wv (512x1024 -> [n][c]); 5=Wo (1024x512 -> [co][j]). bf16 out.
// ---------------------------------------------------------------------------
__global__ __launch_bounds__(256) void ath_tr(
    const float* __restrict__ inp, const float* __restrict__ Wq,
    const float* __restrict__ Wk,  const float* __restrict__ Wv,
    const float* __restrict__ Wo,
    unsigned short* __restrict__ inpT, unsigned short* __restrict__ WT,
    unsigned short* __restrict__ WoT)
{
  const int z = blockIdx.z;
  const float* src; unsigned short* dst; int R, C;
  if      (z == 0) { src = inp;              dst = inpT;                R = 512;  C = 1024; }
  else if (z == 1) { src = inp + 512 * 1024; dst = inpT + 1024 * 512;   R = 512;  C = 1024; }
  else if (z == 2) { src = Wq;               dst = WT;                  R = 512;  C = 1024; }
  else if (z == 3) { src = Wk;               dst = WT + 1024 * 512;     R = 512;  C = 1024; }
  else if (z == 4) { src = Wv;               dst = WT + 2 * 1024 * 512; R = 512;  C = 1024; }
  else             { src = Wo;               dst = WoT;                 R = 1024; C = 512;  }
  const int ct = blockIdx.x, rt = blockIdx.y;
  if (ct * 32 >= C || rt * 32 >= R) return;

  __shared__ float Ts[32][33];
  const int t = threadIdx.x;
  {
    const int r = t >> 3, c4 = (t & 7) * 4;
    const floatx4 g = *(const floatx4*)(src + (size_t)(rt * 32 + r) * C + ct * 32 + c4);
    Ts[r][c4 + 0] = g[0]; Ts[r][c4 + 1] = g[1];
    Ts[r][c4 + 2] = g[2]; Ts[r][c4 + 3] = g[3];
  }
  __syncthreads();
  {
    const int i = t >> 3, k4 = (t & 7) * 4;
    const unsigned int o0 = pkbf(Ts[k4 + 0][i], Ts[k4 + 1][i]);
    const unsigned int o1 = pkbf(Ts[k4 + 2][i], Ts[k4 + 3][i]);
    *(uint2v*)(dst + (size_t)(ct * 32 + i) * R + rt * 32 + k4) = (uint2v){o0, o1};
  }
}

// ---------------------------------------------------------------------------
// K1: QKV projection from pre-transposed bf16 inputs.
// Q,K -> [b][h][s][d] ; V -> [b][v][d][s]. Staging = b128 row copies.
// ---------------------------------------------------------------------------
__global__ __launch_bounds__(256) void ath_qkv(
    const unsigned short* __restrict__ inpT,  // [b][s][c]
    const unsigned short* __restrict__ WT,    // [p][n][c]
    const float* __restrict__ Aq,
    const float* __restrict__ Ak,
    const float* __restrict__ Av,
    unsigned short* __restrict__ ws)
{
  const int sblk = blockIdx.x;
  const int nblk = blockIdx.y;
  const int z = blockIdx.z;
  const int b = z / 3, p = z % 3;
  const float* Ap = (p == 0) ? Aq : ((p == 1) ? Ak : Av);
  const float sig = 1.0f / (1.0f + __expf(-Ap[0]));

  __shared__ __align__(16) unsigned short As[64][40];
  __shared__ __align__(16) unsigned short Bs[64][40];

  const int tid = threadIdx.x;
  const int w = tid >> 6, lane = tid & 63;
  const int l15 = lane & 15, quad = lane >> 4;
  const int srow = tid >> 2, sc8 = (tid & 3) * 8;

  floatx4 acc[4];
#pragma unroll
  for (int i = 0; i < 4; ++i) acc[i] = (floatx4){0.f, 0.f, 0.f, 0.f};

  for (int cc = 0; cc < 16; ++cc) {
    const int c0 = cc * 32;
    __syncthreads();
    *(short8*)&As[srow][sc8] =
        *(const short8*)(inpT + ((size_t)(b * 1024 + sblk * 64 + srow)) * 512 + c0 + sc8);
    *(short8*)&Bs[srow][sc8] =
        *(const short8*)(WT + ((size_t)(p * 1024 + nblk * 64 + srow)) * 512 + c0 + sc8);
    __syncthreads();
    const short8 a = *(const short8*)&As[w * 16 + l15][quad * 8];
#pragma unroll
    for (int nt = 0; nt < 4; ++nt) {
      const short8 bb = *(const short8*)&Bs[nt * 16 + l15][quad * 8];
      acc[nt] = __builtin_amdgcn_mfma_f32_16x16x32_bf16(a, bb, acc[nt], 0, 0, 0);
    }
  }

  unsigned short* out = ws + (size_t)p * ((size_t)B_S * N_H * SEQL * D_K);
#pragma unroll
  for (int nt = 0; nt < 4; ++nt) {
    const int h = l15;
    const int d = nblk * 4 + nt;
#pragma unroll
    for (int r = 0; r < 4; ++r) {
      const int s = sblk * 64 + w * 16 + quad * 4 + r;
      const float vout = acc[nt][r] * sig;
      if (p == 2) out[((size_t)((b * N_H + h) * D_K + d)) * SEQL + s] = f2bf(vout);
      else        out[((size_t)((b * N_H + h) * SEQL + s)) * D_K + d] = f2bf(vout);
    }
  }
}

// ---------------------------------------------------------------------------
// K2a (P path): partial l + P store. KSL2=8: 2 k-chunks of 64 per block;
// Q frags resident across both chunks; dl accumulated; lp slot = ks*4+w.
// ---------------------------------------------------------------------------
__global__ __launch_bounds__(256, 3) void ath_lpartP(
    const float* __restrict__ maskp,
    const float* __restrict__ Wl,
    const unsigned short* __restrict__ qkv,
    float* __restrict__ lp,
    unsigned short* __restrict__ Pws)
{
  const int qblk = blockIdx.x;
  const int ks   = blockIdx.y;         // 0..KSL2-1, covers k-128
  const int b    = blockIdx.z;
  const int tid = threadIdx.x;
  const int w = tid >> 6, lane = tid & 63;
  const int l15 = lane & 15, quad = lane >> 4;

  const unsigned short* Qf = qkv;
  const unsigned short* Kf = qkv + (size_t)B_S * N_H * SEQL * D_K;

  __shared__ unsigned int JtU[9216];  // [q16*64 + k][9] f16 pairs, 36 KB

  const f16x4 wlA = mkh4(pkh2(Wl[(quad * 4 + 0) * 16 + l15], Wl[(quad * 4 + 1) * 16 + l15]),
                         pkh2(Wl[(quad * 4 + 2) * 16 + l15], Wl[(quad * 4 + 3) * 16 + l15]));
  const f16x4 idB = mkh4(pkh2((quad * 4 + 0 == l15) ? 1.f : 0.f, (quad * 4 + 1 == l15) ? 1.f : 0.f),
                         pkh2((quad * 4 + 2 == l15) ? 1.f : 0.f, (quad * 4 + 3 == l15) ? 1.f : 0.f));
  const unsigned int ONE2 = 0x3C003C00u;
  const f16x4 onesB = mkh4(ONE2, ONE2);
  const f16x4 zeroB = mkh4(0u, 0u);

  // ---- resident Q frags for heads 4w..4w+3 (amortized over 2 chunks) ----
  short8 qf0[4], qf1[4];
#pragma unroll
  for (int hh = 0; hh < 4; ++hh) {
    const unsigned short* qb =
        Qf + ((size_t)((b * N_H + w * 4 + hh) * SEQL) + qblk * 16 + l15) * D_K;
    qf0[hh] = *(const short8*)(qb + quad * 8);
    qf1[hh] = *(const short8*)(qb + 32 + quad * 8);
  }

  unsigned int* Pu = (unsigned int*)Pws;
  floatx4 dl0 = (floatx4){0.f, 0.f, 0.f, 0.f};
  floatx4 dl1 = (floatx4){0.f, 0.f, 0.f, 0.f};

  for (int kc = 0; kc < 2; ++kc) {
    const int k0 = ks * 128 + kc * 64;
    const int kabs = k0 + w * 16 + l15;
    const float mreg = maskp[b * SEQL + kabs];  // mask[k=l15]

    // ---- J-phase: K streams only; D rows=q, cols=k ----
#pragma unroll
    for (int kt = 0; kt < 4; ++kt) {
      floatx4 jc[4];
#pragma unroll
      for (int hh = 0; hh < 4; ++hh) {
        const unsigned short* kb =
            Kf + ((size_t)((b * N_H + w * 4 + hh) * SEQL) + k0 + kt * 16 + l15) * D_K;
        const short8 kf0 = *(const short8*)(kb + quad * 8);
        const short8 kf1 = *(const short8*)(kb + 32 + quad * 8);
        floatx4 c = (floatx4){0.f, 0.f, 0.f, 0.f};
        c = __builtin_amdgcn_mfma_f32_16x16x32_bf16(qf0[hh], kf0, c, 0, 0, 0);
        c = __builtin_amdgcn_mfma_f32_16x16x32_bf16(qf1[hh], kf1, c, 0, 0, 0);
        jc[hh] = c;
      }
#pragma unroll
      for (int r = 0; r < 4; ++r) {
        const int base = ((quad * 4 + r) * 64 + kt * 16 + l15) * 9 + w * 2;
        JtU[base + 0] = pkh2(jc[0][r], jc[1][r]);
        JtU[base + 1] = pkh2(jc[2][r], jc[3][r]);
      }
    }

    __syncthreads();  // JtU complete (all waves' h-pairs)

#pragma unroll 4
    for (int q = 0; q < 16; ++q) {
      const int jb = (q * 64 + w * 16 + l15) * 9 + quad * 2;   // B[h=quad*4+j][k=l15]
      const f16x4 bj = mkh4(JtU[jb], JtU[jb + 1]);
      floatx4 d1 = __builtin_amdgcn_mfma_f32_16x16x16f16(
          wlA, bj, (floatx4){0.f, 0.f, 0.f, 0.f}, 0, 0, 0);  // (g rows, k cols)
      float p[4];
#pragma unroll
      for (int r = 0; r < 4; ++r) {
        const float e = fminf(fmaxf(d1[r] - mreg, -60.f), 60.f);
        p[r] = __expf(e);
      }
      const unsigned int u0 = pkh2(p[0], p[1]);
      const unsigned int u1 = pkh2(p[2], p[3]);
      const size_t pidx =
          ((size_t)(b * 1024 + qblk * 16 + q) * 1024 + kabs) * 8 + quad * 2;
      *(uint2v*)&Pu[pidx] = (uint2v){u0, u1};

      const f16x4 ap = mkh4(u0, u1);
      floatx4 dt = __builtin_amdgcn_mfma_f32_16x16x16f16(
          ap, idB, (floatx4){0.f, 0.f, 0.f, 0.f}, 0, 0, 0);   // (k rows, g cols)
      const f16x4 a2 = mkh4(pkh2(dt[0], dt[1]), pkh2(dt[2], dt[3]));  // A[g][k]
      const f16x4 eq = (l15 == q) ? onesB : zeroB;  // B[k][col]=delta(col,q)
      if (q & 1) dl1 = __builtin_amdgcn_mfma_f32_16x16x16f16(a2, eq, dl1, 0, 0, 0);
      else       dl0 = __builtin_amdgcn_mfma_f32_16x16x16f16(a2, eq, dl0, 0, 0, 0);
    }

    __syncthreads();  // JtU free for next chunk's J-phase
  }

  const floatx4 dl = dl0 + dl1;
  // lane (quad,l15): dl[r] = l[q=l15][g=quad*4+r] over this block's k-128
  *(floatx4*)(lp + ((size_t)((ks * 4 + w) * 2 + b)) * 16384 +
              (size_t)(qblk * 16 + l15) * 16 + quad * 4) = dl;
}

// ---------------------------------------------------------------------------
// K2a (fallback): legacy lpart, identical to r18.
// ---------------------------------------------------------------------------
__global__ __launch_bounds__(256, 3) void ath_lpart(
    const float* __restrict__ maskp,
    const float* __restrict__ Wl,
    const unsigned short* __restrict__ qkv,
    float* __restrict__ lp)
{
  const int qblk = blockIdx.x;
  const int ks   = blockIdx.y;
  const int b    = blockIdx.z;
  const int tid = threadIdx.x;
  const int w = tid >> 6, lane = tid & 63;
  const int l15 = lane & 15, quad = lane >> 4;

  const unsigned short* Qf = qkv;
  const unsigned short* Kf = qkv + (size_t)B_S * N_H * SEQL * D_K;

  __shared__ unsigned int JtU[9216];

  const f16x4 wlA = mkh4(pkh2(Wl[(quad * 4 + 0) * 16 + l15], Wl[(quad * 4 + 1) * 16 + l15]),
                         pkh2(Wl[(quad * 4 + 2) * 16 + l15], Wl[(quad * 4 + 3) * 16 + l15]));
  const f16x4 idB = mkh4(pkh2((quad * 4 + 0 == l15) ? 1.f : 0.f, (quad * 4 + 1 == l15) ? 1.f : 0.f),
                         pkh2((quad * 4 + 2 == l15) ? 1.f : 0.f, (quad * 4 + 3 == l15) ? 1.f : 0.f));
  const unsigned int ONE2 = 0x3C003C00u;
  const f16x4 onesB = mkh4(ONE2, ONE2);
  const f16x4 zeroB = mkh4(0u, 0u);

  const float mreg = maskp[b * SEQL + ks * 64 + w * 16 + l15];
  const int k0 = ks * 64;

  short8 qf0[4], qf1[4];
#pragma unroll
  for (int hh = 0; hh < 4; ++hh) {
    const unsigned short* qb =
        Qf + ((size_t)((b * N_H + w * 4 + hh) * SEQL) + qblk * 16 + l15) * D_K;
    qf0[hh] = *(const short8*)(qb + quad * 8);
    qf1[hh] = *(const short8*)(qb + 32 + quad * 8);
  }

#pragma unroll
  for (int kt = 0; kt < 4; ++kt) {
    floatx4 jc[4];
#pragma unroll
    for (int hh = 0; hh < 4; ++hh) {
      const unsigned short* kb =
          Kf + ((size_t)((b * N_H + w * 4 + hh) * SEQL) + k0 + kt * 16 + l15) * D_K;
      const short8 kf0 = *(const short8*)(kb + quad * 8);
      const short8 kf1 = *(const short8*)(kb + 32 + quad * 8);
      floatx4 c = (floatx4){0.f, 0.f, 0.f, 0.f};
      c = __builtin_amdgcn_mfma_f32_16x16x32_bf16(qf0[hh], kf0, c, 0, 0, 0);
      c = __builtin_amdgcn_mfma_f32_16x16x32_bf16(qf1[hh], kf1, c, 0, 0, 0);
      jc[hh] = c;
    }
#pragma unroll
    for (int r = 0; r < 4; ++r) {
      const int base = ((quad * 4 + r) * 64 + kt * 16 + l15) * 9 + w * 2;
      JtU[base + 0] = pkh2(jc[0][r], jc[1][r]);
      JtU[base + 1] = pkh2(jc[2][r], jc[3][r]);
    }
  }

  __syncthreads();

  floatx4 dl0 = (floatx4){0.f, 0.f, 0.f, 0.f};
  floatx4 dl1 = (floatx4){0.f, 0.f, 0.f, 0.f};
#pragma unroll 4
  for (int q = 0; q < 16; ++q) {
    const int jb = (q * 64 + w * 16 + l15) * 9 + quad * 2;
    const f16x4 bj = mkh4(JtU[jb], JtU[jb + 1]);
    floatx4 d1 = __builtin_amdgcn_mfma_f32_16x16x16f16(
        wlA, bj, (floatx4){0.f, 0.f, 0.f, 0.f}, 0, 0, 0);
    float p[4];
#pragma unroll
    for (int r = 0; r < 4; ++r) {
      const float e = fminf(fmaxf(d1[r] - mreg, -60.f), 60.f);
      p[r] = __expf(e);
    }
    const f16x4 ap = mkh4(pkh2(p[0], p[1]), pkh2(p[2], p[3]));
    floatx4 dt = __builtin_amdgcn_mfma_f32_16x16x16f16(
        ap, idB, (floatx4){0.f, 0.f, 0.f, 0.f}, 0, 0, 0);
    const f16x4 a2 = mkh4(pkh2(dt[0], dt[1]), pkh2(dt[2], dt[3]));
    const f16x4 eq = (l15 == q) ? onesB : zeroB;
    if (q & 1) dl1 = __builtin_amdgcn_mfma_f32_16x16x16f16(a2, eq, dl1, 0, 0, 0);
    else       dl0 = __builtin_amdgcn_mfma_f32_16x16x16f16(a2, eq, dl0, 0, 0, 0);
  }
  const floatx4 dl = dl0 + dl1;

  *(floatx4*)(lp + ((size_t)((ks * 4 + w) * 2 + b)) * 16384 +
              (size_t)(qblk * 16 + l15) * 16 + quad * 4) = dl;
}

// ---------------------------------------------------------------------------
// K2r: invl = 1 / sum over nsl per-wave slots. grid(128, 256 thr).
// ---------------------------------------------------------------------------
__global__ __launch_bounds__(256) void ath_linv(
    const float* __restrict__ lp, float* __restrict__ invl, int nsl)
{
  const int t = blockIdx.x * 256 + threadIdx.x;
  const int b = t >> 14, rem = t & 16383;
  float s = 0.f;
  for (int sl = 0; sl < nsl; ++sl) s += lp[(size_t)(sl * 2 + b) * 16384 + rem];
  invl[t] = 1.0f / fmaxf(s, 1e-37f);
}

// ---------------------------------------------------------------------------
// K2b (P path): d-split partial O, KSO=4 (k-256/block over 4 rds).
// grid(64, 4, 4: z=b*2+dh) = 1024 blocks; (256,3).
// ---------------------------------------------------------------------------
__global__ __launch_bounds__(256, 3) void ath_opartP(
    const unsigned short* __restrict__ Pws,   // [b][q][k][g16] f16 unnorm
    const float* __restrict__ Ww,
    const unsigned short* __restrict__ qkv,
    const float* __restrict__ invl,
    unsigned short* __restrict__ Obp)
{
  const int qblk = blockIdx.x;
  const int ks   = blockIdx.y;
  const int z    = blockIdx.z;          // b*2 + dh
  const int b = z >> 1, dh = z & 1;
  const int tid = threadIdx.x;
  const int w = tid >> 6, lane = tid & 63;
  const int l15 = lane & 15, quad = lane >> 4;

  const unsigned short* Vf = qkv + 2 * (size_t)B_S * N_H * SEQL * D_K;

  __shared__ __align__(16) unsigned short Us[16 * 16 * 64];  // 32 KB, swizzled
  __shared__ float invls[16][16];

  invls[tid >> 4][tid & 15] =
      invl[(size_t)b * 16384 + (qblk * 16 + (tid >> 4)) * 16 + (tid & 15)];

  const f16x4 wwB = mkh4(pkh2(Ww[(quad * 4 + 0) * 16 + l15], Ww[(quad * 4 + 1) * 16 + l15]),
                         pkh2(Ww[(quad * 4 + 2) * 16 + l15], Ww[(quad * 4 + 3) * 16 + l15]));

  floatx4 oacc[4][2];
#pragma unroll
  for (int a = 0; a < 4; ++a)
#pragma unroll
    for (int d = 0; d < 2; ++d) oacc[a][d] = (floatx4){0.f, 0.f, 0.f, 0.f};

  const unsigned int* Pu = (const unsigned int*)Pws;

  __syncthreads();  // invls visible

  for (int rd = 0; rd < 4; ++rd) {
    const int kabs = ks * 256 + rd * 64 + w * 16 + l15;

    // ---- mix: read P (batches of 8 q), x inv, U-mfma, swizzled Us write ----
#pragma unroll
    for (int qh = 0; qh < 2; ++qh) {
      uint2v pv[8];
#pragma unroll
      for (int qq = 0; qq < 8; ++qq) {
        const size_t pidx =
            ((size_t)(b * 1024 + qblk * 16 + qh * 8 + qq) * 1024 + kabs) * 8 + quad * 2;
        pv[qq] = *(const uint2v*)&Pu[pidx];
      }
#pragma unroll
      for (int qq = 0; qq < 8; ++qq) {
        const int q = qh * 8 + qq;
        const floatx4 iq = *(const floatx4*)&invls[q][quad * 4];
        union { unsigned int u; _Float16 h[2]; } z0, z1;
        z0.u = pv[qq][0]; z1.u = pv[qq][1];
        const f16x4 ap = mkh4(pkh2((float)z0.h[0] * iq[0], (float)z0.h[1] * iq[1]),
                              pkh2((float)z1.h[0] * iq[2], (float)z1.h[1] * iq[3]));
        floatx4 d2 = __builtin_amdgcn_mfma_f32_16x16x16f16(
            ap, wwB, (floatx4){0.f, 0.f, 0.f, 0.f}, 0, 0, 0);  // U: k rows, v=l15
        const int row = l15 * 16 + q;
        const int ch = (w * 2 + (quad >> 1)) ^ ((l15 ^ q) & 7);
        *(uint2v*)&Us[row * 64 + ch * 8 + (quad & 1) * 4] =
            (uint2v){pkbf(d2[0], d2[1]), pkbf(d2[2], d2[3])};
      }
    }

    __syncthreads();  // all waves' Us slices ready

    // ---- V-phase: wave w -> v = 4w..4w+3; d-tiles dh*2+dt (dt 0..1) ----
#pragma unroll
    for (int tp = 0; tp < 2; ++tp) {
      const int kt_abs = ks * 256 + rd * 64 + tp * 32;
#pragma unroll
      for (int vv = 0; vv < 4; ++vv) {
        const int v = w * 4 + vv;
        const int ch = (tp * 4 + quad) ^ ((v ^ l15) & 7);
        const short8 ufr = *(const short8*)&Us[(v * 16 + l15) * 64 + ch * 8];
#pragma unroll
        for (int dt = 0; dt < 2; ++dt) {
          const int dtile = dh * 2 + dt;
          const short8 vfr = *(const short8*)(Vf +
              ((size_t)((b * N_H + v) * D_K + dtile * 16 + l15)) * SEQL + kt_abs + quad * 8);
          oacc[vv][dt] = __builtin_amdgcn_mfma_f32_16x16x32_bf16(ufr, vfr, oacc[vv][dt], 0, 0, 0);
        }
      }
    }

    __syncthreads();  // Us free for next rd
  }

#pragma unroll
  for (int vv = 0; vv < 4; ++vv) {
    const int v = w * 4 + vv;
#pragma unroll
    for (int dt = 0; dt < 2; ++dt) {
      const int d = (dh * 2 + dt) * 16 + l15;
#pragma unroll
      for (int r = 0; r < 4; ++r) {
        const int q = qblk * 16 + quad * 4 + r;
        Obp[(size_t)ks * BQJ + ((size_t)(b * SEQL + q)) * 1024 + d * 16 + v] = f2bf(oacc[vv][dt][r]);
      }
    }
  }
}

// ---------------------------------------------------------------------------
// K2b (fallback): legacy opart, identical to r18 (KSO_LEG=8 split).
// ---------------------------------------------------------------------------
__global__ __launch_bounds__(256, 2) void ath_opart(
    const float* __restrict__ maskp,
    const float* __restrict__ Wl,
    const float* __restrict__ Ww,
    const unsigned short* __restrict__ qkv,
    const float* __restrict__ invl,
    unsigned short* __restrict__ Obp)
{
  const int qblk = blockIdx.x;
  const int ks   = blockIdx.y;
  const int b    = blockIdx.z;
  const int tid = threadIdx.x;
  const int w = tid >> 6, lane = tid & 63;
  const int l15 = lane & 15, quad = lane >> 4;

  const unsigned short* Qf = qkv;
  const unsigned short* Kf = qkv + (size_t)B_S * N_H * SEQL * D_K;
  const unsigned short* Vf = qkv + 2 * (size_t)B_S * N_H * SEQL * D_K;

  __shared__ unsigned int JtU[9216];
  __shared__ float invls[16][16];

  invls[tid >> 4][tid & 15] =
      invl[(size_t)b * 16384 + (qblk * 16 + (tid >> 4)) * 16 + (tid & 15)];

  const f16x4 wlA = mkh4(pkh2(Wl[(quad * 4 + 0) * 16 + l15], Wl[(quad * 4 + 1) * 16 + l15]),
                         pkh2(Wl[(quad * 4 + 2) * 16 + l15], Wl[(quad * 4 + 3) * 16 + l15]));
  const f16x4 wwB = mkh4(pkh2(Ww[(quad * 4 + 0) * 16 + l15], Ww[(quad * 4 + 1) * 16 + l15]),
                         pkh2(Ww[(quad * 4 + 2) * 16 + l15], Ww[(quad * 4 + 3) * 16 + l15]));

  short8 qf0[4], qf1[4];
#pragma unroll
  for (int hh = 0; hh < 4; ++hh) {
    const unsigned short* qb =
        Qf + ((size_t)((b * N_H + w * 4 + hh) * SEQL) + qblk * 16 + l15) * D_K;
    qf0[hh] = *(const short8*)(qb + quad * 8);
    qf1[hh] = *(const short8*)(qb + 32 + quad * 8);
  }

  floatx4 oacc[4][4];
#pragma unroll
  for (int a = 0; a < 4; ++a)
#pragma unroll
    for (int d = 0; d < 4; ++d) oacc[a][d] = (floatx4){0.f, 0.f, 0.f, 0.f};

  __syncthreads();

  for (int rd = 0; rd < 2; ++rd) {
    const int k0 = ks * 128 + rd * 64;
    const float mreg = maskp[b * SEQL + k0 + w * 16 + l15];

#pragma unroll
    for (int kt = 0; kt < 4; ++kt) {
      floatx4 jc[4];
#pragma unroll
      for (int hh = 0; hh < 4; ++hh) {
        const unsigned short* kb =
            Kf + ((size_t)((b * N_H + w * 4 + hh) * SEQL) + k0 + kt * 16 + l15) * D_K;
        const short8 kf0 = *(const short8*)(kb + quad * 8);
        const short8 kf1 = *(const short8*)(kb + 32 + quad * 8);
        floatx4 c = (floatx4){0.f, 0.f, 0.f, 0.f};
        c = __builtin_amdgcn_mfma_f32_16x16x32_bf16(qf0[hh], kf0, c, 0, 0, 0);
        c = __builtin_amdgcn_mfma_f32_16x16x32_bf16(qf1[hh], kf1, c, 0, 0, 0);
        jc[hh] = c;
      }
#pragma unroll
      for (int r = 0; r < 4; ++r) {
        const int base = ((quad * 4 + r) * 64 + kt * 16 + l15) * 9 + w * 2;
        JtU[base + 0] = pkh2(jc[0][r], jc[1][r]);
        JtU[base + 1] = pkh2(jc[2][r], jc[3][r]);
      }
    }

    __syncthreads();

#pragma unroll 4
    for (int q = 0; q < 16; ++q) {
      const int jb = (q * 64 + w * 16 + l15) * 9 + quad * 2;
      const f16x4 bj = mkh4(JtU[jb], JtU[jb + 1]);
      floatx4 d1 = __builtin_amdgcn_mfma_f32_16x16x16f16(
          wlA, bj, (floatx4){0.f, 0.f, 0.f, 0.f}, 0, 0, 0);
      const floatx4 iq = *(const floatx4*)&invls[q][quad * 4];
      float p[4];
#pragma unroll
      for (int r = 0; r < 4; ++r) {
        const float e = fminf(fmaxf(d1[r] - mreg, -60.f), 60.f);
        p[r] = __expf(e) * iq[r];
      }
      const f16x4 ap = mkh4(pkh2(p[0], p[1]), pkh2(p[2], p[3]));
      floatx4 d2 = __builtin_amdgcn_mfma_f32_16x16x16f16(
          ap, wwB, (floatx4){0.f, 0.f, 0.f, 0.f}, 0, 0, 0);
      const int ub = (q * 64 + w * 16) * 9 + ((l15 + q) & 15) * 8 + quad * 2;
      *(uint2v*)&JtU[ub] = (uint2v){pkbf(d2[0], d2[1]), pkbf(d2[2], d2[3])};
    }

    __syncthreads();

    const unsigned short* JtS = (const unsigned short*)JtU;
#pragma unroll
    for (int tp = 0; tp < 2; ++tp) {
      const int kt_abs = ks * 128 + rd * 64 + tp * 32;
#pragma unroll
      for (int vv = 0; vv < 4; ++vv) {
        const int v = w * 4 + vv;
        const int wp = tp * 2 + (quad >> 1);
        const int so = (l15 * 64 + wp * 16) * 18 + ((v + l15) & 15) * 16 + (quad & 1) * 8;
        const short8 ufr = *(const short8*)&JtS[so];
#pragma unroll
        for (int dt = 0; dt < 4; ++dt) {
          const short8 vfr = *(const short8*)(Vf +
              ((size_t)((b * N_H + v) * D_K + dt * 16 + l15)) * SEQL + kt_abs + quad * 8);
          oacc[vv][dt] = __builtin_amdgcn_mfma_f32_16x16x32_bf16(ufr, vfr, oacc[vv][dt], 0, 0, 0);
        }
      }
    }

    __syncthreads();
  }

#pragma unroll
  for (int vv = 0; vv < 4; ++vv) {
    const int v = w * 4 + vv;
#pragma unroll
    for (int dt = 0; dt < 4; ++dt) {
      const int d = dt * 16 + l15;
#pragma unroll
      for (int r = 0; r < 4; ++r) {
        const int q = qblk * 16 + quad * 4 + r;
        Obp[(size_t)ks * BQJ + ((size_t)(b * SEQL + q)) * 1024 + d * 16 + v] = f2bf(oacc[vv][dt][r]);
      }
    }
  }
}

// ---------------------------------------------------------------------------
// K2s: Obsum = sum over nks Obp partials. grid(1024, 256 thr).
// ---------------------------------------------------------------------------
__global__ __launch_bounds__(256) void ath_osum(
    const unsigned short* __restrict__ Obp,
    unsigned short* __restrict__ Obsum, int nks)
{
  const size_t i = ((size_t)blockIdx.x * 256 + threadIdx.x) * 8;
  float a[8];
#pragma unroll
  for (int e = 0; e < 8; ++e) a[e] = 0.f;
  for (int ks = 0; ks < nks; ++ks) {
    const short8 v = *(const short8*)(Obp + (size_t)ks * BQJ + i);
#pragma unroll
    for (int e = 0; e < 8; ++e) a[e] += bf2f((unsigned short)v[e]);
  }
  short8 o;
#pragma unroll
  for (int e = 0; e < 8; ++e) o[e] = (short)f2bf(a[e]);
  *(short8*)(Obsum + i) = o;
}

// ---------------------------------------------------------------------------
// K3: out[b][co][q] = inp + sum_j Obsum[b][q][j] * WoT[co][j]. fp32 out.
// ---------------------------------------------------------------------------
__global__ __launch_bounds__(256) void ath_out(
    const float* __restrict__ inp,
    const unsigned short* __restrict__ WoT,   // [co][j] bf16
    const unsigned short* __restrict__ Ob,
    float* __restrict__ out)
{
  const int qblk = blockIdx.x;
  const int cblk = blockIdx.y;
  const int b    = blockIdx.z;
  const int tid = threadIdx.x;
  const int w = tid >> 6, lane = tid & 63;
  const int l15 = lane & 15, quad = lane >> 4;

  __shared__ __align__(16) unsigned short Os[64][40];
  __shared__ __align__(16) unsigned short Wt[64][40];

  floatx4 acc[4];
#pragma unroll
  for (int i = 0; i < 4; ++i) acc[i] = (floatx4){0.f, 0.f, 0.f, 0.f};

  const int srow = tid >> 2, sj8 = (tid & 3) * 8;

  for (int jc = 0; jc < 32; ++jc) {
    const int j0 = jc * 32;
    __syncthreads();
    *(short8*)&Os[srow][sj8] =
        *(const short8*)(Ob + ((size_t)(b * SEQL + qblk * 64 + srow)) * 1024 + j0 + sj8);
    *(short8*)&Wt[srow][sj8] =
        *(const short8*)(WoT + ((size_t)(cblk * 64 + srow)) * 1024 + j0 + sj8);
    __syncthreads();
    const short8 a = *(const short8*)&Os[w * 16 + l15][quad * 8];
#pragma unroll
    for (int nt = 0; nt < 4; ++nt) {
      const short8 bb = *(const short8*)&Wt[nt * 16 + l15][quad * 8];
      acc[nt] = __builtin_amdgcn_mfma_f32_16x16x32_bf16(a, bb, acc[nt], 0, 0, 0);
    }
  }

#pragma unroll
  for (int nt = 0; nt < 4; ++nt) {
    const int co = cblk * 64 + nt * 16 + l15;
    const int qb = qblk * 64 + w * 16 + quad * 4;
    const float* ip = inp + ((size_t)(b * 512 + co)) * SEQL + qb;
    float* op = out + ((size_t)(b * 512 + co)) * SEQL + qb;
#pragma unroll
    for (int r = 0; r < 4; ++r) op[r] = acc[nt][r] + ip[r];
  }
}

// ---------------------------------------------------------------------------
extern "C" void kernel_launch(void* const* d_in, const int* in_sizes, int n_in,
                              void* d_out, int out_size, void* d_ws, size_t ws_size,
                              hipStream_t stream) {
  (void)in_sizes; (void)n_in; (void)out_size;
  const float* inp   = (const float*)d_in[0];
  const float* maskp = (const float*)d_in[1];
  const float* Wq    = (const float*)d_in[2];
  const float* Wk    = (const float*)d_in[3];
  const float* Wv    = (const float*)d_in[4];
  const float* Aq    = (const float*)d_in[5];
  const float* Ak    = (const float*)d_in[6];
  const float* Av    = (const float*)d_in[7];
  const float* Wl    = (const float*)d_in[8];
  const float* Ww    = (const float*)d_in[9];
  const float* Wo    = (const float*)d_in[10];

  const size_t MB = 1u << 20;
  unsigned short* qkv   = (unsigned short*)d_ws;                       // [0,12) Q,K,V bf16
  unsigned short* Obsum = (unsigned short*)((char*)d_ws + 12 * MB);    // [12,16)
  float*          invl  = (float*)((char*)d_ws + 16 * MB);             // 128 KB
  unsigned short* WoT   = (unsigned short*)((char*)d_ws + 17 * MB);    // [17,18)
  float*          lp    = (float*)((char*)d_ws + 18 * MB);             // [18,26)
  unsigned short* WT    = (unsigned short*)((char*)d_ws + 26 * MB);    // [26,29)
  unsigned short* inpT  = (unsigned short*)((char*)d_ws + 29 * MB);    // [29,31)
  unsigned short* Obp   = (unsigned short*)((char*)d_ws + 18 * MB);    // [18,34)/[18,50) after linv
  unsigned short* Pws   = (unsigned short*)((char*)d_ws + 50 * MB);    // [50,114) P cache
  float* out = (float*)d_out;

  const bool useP = ws_size >= (size_t)114 * MB;

  ath_tr<<<dim3(32, 32, 6), 256, 0, stream>>>(inp, Wq, Wk, Wv, Wo, inpT, WT, WoT);
  ath_qkv<<<dim3(16, 16, 6), 256, 0, stream>>>(inpT, WT, Aq, Ak, Av, qkv);
  if (useP) {
    ath_lpartP<<<dim3(64, KSL2, 2), 256, 0, stream>>>(maskp, Wl, qkv, lp, Pws);
    ath_linv<<<dim3(128), 256, 0, stream>>>(lp, invl, KSL2 * 4);
    ath_opartP<<<dim3(64, KSO, 4), 256, 0, stream>>>(Pws, Ww, qkv, invl, Obp);
    ath_osum<<<dim3(1024), 256, 0, stream>>>(Obp, Obsum, KSO);
  } else {
    ath_lpart<<<dim3(64, KSL, 2), 256, 0, stream>>>(maskp, Wl, qkv, lp);
    ath_linv<<<dim3(128), 256, 0, stream>>>(lp, invl, KSL * 4);
    ath_opart<<<dim3(64, KSO_LEG, 2), 256, 0, stream>>>(maskp, Wl, Ww, qkv, invl, Obp);
    ath_osum<<<dim3(1024), 256, 0, stream>>>(Obp, Obsum, KSO_LEG);
  }
  ath_out<<<dim3(16, 8, 2), 256, 0, stream>>>(inp, WoT, Obsum, out);
}